// Round 2
// baseline (1928.884 us; speedup 1.0000x reference)
//
#include <hip/hip_runtime.h>
#include <math.h>

#define BATCH   4
#define LSEQ    2048
#define DMODEL  1024
#define DSTATE  128
#define HEADDIM 64
#define DINNER  2048
#define NHEADS  32
#define CONVCH  2304
#define DINPROJ 4384
#define CHUNKL  128
#define NCHUNK  16
#define ROWS    (BATCH*LSEQ)

// ---------------- workspace layout (BYTE offsets) ----------------
// bf16 storage for fat tensors; fp32 for dt and asum.
#define B_Z     ((size_t)0)                              // ROWS*DINNER bf16   (k2->k8)
#define B_XBC   (B_Z   + (size_t)ROWS*DINNER*2)          // ROWS*CONVCH bf16   (k2->k4); S bf16 aliases (k5->k7)
#define B_DT    (B_XBC + (size_t)ROWS*CONVCH*2)          // ROWS*NHEADS fp32   (k2->k7)
#define B_XS    (B_DT  + (size_t)ROWS*NHEADS*4)          // ROWS*DINNER bf16   (k4->k7)
#define B_BC    (B_XS  + (size_t)ROWS*DINNER*2)          // ROWS*256 bf16      (k4->k7)
#define B_Y     (B_BC  + (size_t)ROWS*256*2)             // ROWS*DINNER bf16   (k7->k9); h bf16 aliases (k1->k2)
#define B_ASUM  (B_Y   + (size_t)ROWS*DINNER*2)          // BATCH*NCHUNK*NHEADS fp32
#define B_END   (B_ASUM + (size_t)BATCH*NCHUNK*NHEADS*4) // ~137 MB total

__device__ __forceinline__ float b2f(ushort u) {
  union { uint32_t i; float f; } v; v.i = ((uint32_t)u) << 16; return v.f;
}
__device__ __forceinline__ ushort f2b(float f) {
  union { float f; uint32_t i; } v; v.f = f;
  uint32_t r = (v.i + 0x7FFFu + ((v.i >> 16) & 1u)) >> 16;
  return (ushort)r;
}

// ---------------- LayerNorm -> h (bf16) ----------------
__global__ __launch_bounds__(256) void ln_kernel(const float* __restrict__ x,
    const float* __restrict__ w, const float* __restrict__ bias, ushort* __restrict__ h)
{
  const int row = blockIdx.x;
  const int t = threadIdx.x;
  const float* xr = x + (size_t)row * DMODEL;
  float v[4];
  float s = 0.f;
  #pragma unroll
  for (int i = 0; i < 4; i++) { v[i] = xr[t + i*256]; s += v[i]; }
  __shared__ float red[4];
  #pragma unroll
  for (int o = 32; o > 0; o >>= 1) s += __shfl_down(s, o, 64);
  if ((t & 63) == 0) red[t >> 6] = s;
  __syncthreads();
  float mean = (red[0]+red[1]+red[2]+red[3]) * (1.f/DMODEL);
  float vs = 0.f;
  #pragma unroll
  for (int i = 0; i < 4; i++) { float d = v[i]-mean; vs += d*d; }
  #pragma unroll
  for (int o = 32; o > 0; o >>= 1) vs += __shfl_down(vs, o, 64);
  __syncthreads();
  if ((t & 63) == 0) red[t >> 6] = vs;
  __syncthreads();
  float rstd = rsqrtf((red[0]+red[1]+red[2]+red[3]) * (1.f/DMODEL) + 1e-5f);
  ushort* hr = h + (size_t)row * DMODEL;
  #pragma unroll
  for (int i = 0; i < 4; i++) {
    int c = t + i*256;
    hr[c] = f2b((v[i]-mean)*rstd*w[c] + bias[c]);
  }
}

// ---------------- in_proj GEMM: [ROWS][4384] = h[ROWS][1024] @ W[4384][1024]^T ----------------
__global__ __launch_bounds__(256) void gemm_inproj_kernel(
    const ushort* __restrict__ A, const float* __restrict__ W,
    ushort* __restrict__ z, ushort* __restrict__ xbc, float* __restrict__ dtr)
{
  __shared__ float As[16][132];
  __shared__ float Bs[16][132];
  const int tid = threadIdx.x;
  const int tx = tid & 15, ty = tid >> 4;
  const int m0 = blockIdx.x * 128;
  const int n0 = blockIdx.y * 128;
  float acc[8][8];
  #pragma unroll
  for (int i = 0; i < 8; i++)
    #pragma unroll
    for (int j = 0; j < 8; j++) acc[i][j] = 0.f;
  for (int k0 = 0; k0 < DMODEL; k0 += 16) {
    #pragma unroll
    for (int u = 0; u < 2; u++) {
      int idx = tid + u*256;
      int r = idx >> 2;
      int kv = (idx & 3) << 2;
      ushort4 av = *(const ushort4*)(A + (size_t)(m0 + r)*DMODEL + k0 + kv);
      As[kv+0][r] = b2f(av.x); As[kv+1][r] = b2f(av.y);
      As[kv+2][r] = b2f(av.z); As[kv+3][r] = b2f(av.w);
      float4 bv = make_float4(0.f, 0.f, 0.f, 0.f);
      if (n0 + r < DINPROJ) bv = *(const float4*)(W + (size_t)(n0 + r)*DMODEL + k0 + kv);
      Bs[kv+0][r] = bv.x; Bs[kv+1][r] = bv.y; Bs[kv+2][r] = bv.z; Bs[kv+3][r] = bv.w;
    }
    __syncthreads();
    for (int k = 0; k < 16; k++) {
      float a[8], bb[8];
      *(float4*)&a[0]  = *(const float4*)&As[k][ty*8];
      *(float4*)&a[4]  = *(const float4*)&As[k][ty*8+4];
      *(float4*)&bb[0] = *(const float4*)&Bs[k][tx*8];
      *(float4*)&bb[4] = *(const float4*)&Bs[k][tx*8+4];
      #pragma unroll
      for (int i = 0; i < 8; i++)
        #pragma unroll
        for (int j = 0; j < 8; j++) acc[i][j] = fmaf(a[i], bb[j], acc[i][j]);
    }
    __syncthreads();
  }
  // route columns: [0,2048) -> z (bf16), [2048,4352) -> xbc (bf16), [4352,4384) -> dtr (fp32)
  #pragma unroll
  for (int i = 0; i < 8; i++) {
    int row = m0 + ty*8 + i;
    #pragma unroll
    for (int j = 0; j < 8; j++) {
      int cg = n0 + tx*8 + j;
      float vv = acc[i][j];
      if (cg < DINNER) {
        z[(size_t)row*DINNER + cg] = f2b(vv);
      } else if (cg < DINNER + CONVCH) {
        xbc[(size_t)row*CONVCH + (cg - DINNER)] = f2b(vv);
      } else if (cg < DINPROJ) {
        dtr[(size_t)row*NHEADS + (cg - DINNER - CONVCH)] = vv;
      }
    }
  }
}

// ---------------- dt = softplus(dt_raw + bias), in place (fp32) ----------------
__global__ __launch_bounds__(256) void dt_kernel(float* __restrict__ dtr, const float* __restrict__ dtb)
{
  int i = blockIdx.x*256 + threadIdx.x;
  float v = dtr[i] + dtb[i & (NHEADS-1)];
  dtr[i] = (v > 20.f) ? v : log1pf(expf(v));
}

// ---------------- causal conv4 + SiLU, split xs / BC (bf16 in/out) ----------------
__global__ __launch_bounds__(256) void conv_kernel(const ushort* __restrict__ xbc,
    const float* __restrict__ cw, const float* __restrict__ cb,
    ushort* __restrict__ xs, ushort* __restrict__ bcb)
{
  int ch  = blockIdx.x*256 + threadIdx.x;   // 0..2303
  int row = blockIdx.y;                     // b*LSEQ + l
  int l = row & (LSEQ-1);
  float acc = cb[ch];
  #pragma unroll
  for (int k = 0; k < 4; k++) {
    int t = l + k - 3;
    if (t >= 0) acc = fmaf(b2f(xbc[(size_t)(row + k - 3)*CONVCH + ch]), cw[ch*4 + k], acc);
  }
  float v = acc / (1.f + expf(-acc));
  if (ch < DINNER) xs[(size_t)row*DINNER + ch] = f2b(v);
  else             bcb[(size_t)row*256 + (ch - DINNER)] = f2b(v);
}

// ---------------- per-chunk states: S[b,c,h,p,n] (bf16 out) ----------------
__global__ __launch_bounds__(256) void states_kernel(
    const ushort* __restrict__ xs, const ushort* __restrict__ bcb, const float* __restrict__ dt,
    const float* __restrict__ A_log, ushort* __restrict__ S, float* __restrict__ asum)
{
  const int hh = blockIdx.x, c = blockIdx.y, b = blockIdx.z;
  __shared__ float Bsm[CHUNKL][DSTATE];   // 64 KB
  __shared__ float Xsm[CHUNKL][HEADDIM];  // 32 KB
  __shared__ float dts[CHUNKL], acs[CHUNKL];
  const int tid = threadIdx.x;
  const int rbase = b*LSEQ + c*CHUNKL;
  if (tid < CHUNKL) dts[tid] = dt[(size_t)(rbase + tid)*NHEADS + hh];
  __syncthreads();
  if (tid == 0) {
    float Aval = -expf(A_log[hh]);
    float s = 0.f;
    for (int l = 0; l < CHUNKL; l++) { s += dts[l]*Aval; acs[l] = s; }
    asum[(b*NCHUNK + c)*NHEADS + hh] = s;
  }
  __syncthreads();
  const float alast = acs[CHUNKL-1];
  for (int i = tid; i < CHUNKL*DSTATE; i += 256) {
    int l = i >> 7, n = i & 127;
    Bsm[l][n] = b2f(bcb[(size_t)(rbase + l)*256 + n]);
  }
  for (int i = tid; i < CHUNKL*HEADDIM; i += 256) {
    int l = i >> 6, p = i & 63;
    Xsm[l][p] = b2f(xs[(size_t)(rbase + l)*DINNER + hh*HEADDIM + p]) * dts[l] * expf(alast - acs[l]);
  }
  __syncthreads();
  const int n0 = (tid & 31) * 4, p0 = (tid >> 5) * 8;
  float acc[8][4];
  #pragma unroll
  for (int i = 0; i < 8; i++) { acc[i][0]=0.f; acc[i][1]=0.f; acc[i][2]=0.f; acc[i][3]=0.f; }
  for (int l = 0; l < CHUNKL; l++) {
    float4 bv = *(const float4*)&Bsm[l][n0];
    float xv[8];
    *(float4*)&xv[0] = *(const float4*)&Xsm[l][p0];
    *(float4*)&xv[4] = *(const float4*)&Xsm[l][p0+4];
    #pragma unroll
    for (int i = 0; i < 8; i++) {
      acc[i][0] = fmaf(xv[i], bv.x, acc[i][0]);
      acc[i][1] = fmaf(xv[i], bv.y, acc[i][1]);
      acc[i][2] = fmaf(xv[i], bv.z, acc[i][2]);
      acc[i][3] = fmaf(xv[i], bv.w, acc[i][3]);
    }
  }
  ushort* Sp = S + (size_t)((b*NCHUNK + c)*NHEADS + hh) * (HEADDIM*DSTATE);
  #pragma unroll
  for (int i = 0; i < 8; i++) {
    ushort4 sv;
    sv.x = f2b(acc[i][0]); sv.y = f2b(acc[i][1]);
    sv.z = f2b(acc[i][2]); sv.w = f2b(acc[i][3]);
    *(ushort4*)&Sp[(p0+i)*DSTATE + n0] = sv;
  }
}

// ---------------- inter-chunk scan (in place: S becomes prev_states P), fp32 carry ----------------
__global__ __launch_bounds__(256) void scan_kernel(ushort* __restrict__ S, const float* __restrict__ asum)
{
  const int hh = blockIdx.x, b = blockIdx.y;
  const int tid = threadIdx.x;
  float carry[32];
  #pragma unroll
  for (int i = 0; i < 32; i++) carry[i] = 0.f;
  for (int c = 0; c < NCHUNK; c++) {
    ushort* Sp = S + (size_t)((b*NCHUNK + c)*NHEADS + hh) * 8192;
    float dec = expf(asum[(b*NCHUNK + c)*NHEADS + hh]);
    #pragma unroll
    for (int i = 0; i < 32; i++) {
      float sv = b2f(Sp[tid + i*256]);
      Sp[tid + i*256] = f2b(carry[i]);
      carry[i] = fmaf(dec, carry[i], sv);
    }
  }
}

// ---------------- Y = Y_diag + Y_off + D*xs (bf16 out) ----------------
__global__ __launch_bounds__(256) void yssd_kernel(
    const ushort* __restrict__ xs, const ushort* __restrict__ bcb, const float* __restrict__ dt,
    const float* __restrict__ A_log, const float* __restrict__ Dvec,
    const ushort* __restrict__ S, ushort* __restrict__ y)
{
  const int hh = blockIdx.x, c = blockIdx.y, b = blockIdx.z;
  __shared__ float R1[128*132];  // CsT[n][l] -> Xs[s][64]
  __shared__ float R2[128*132];  // BsT[n][s] -> PT[n][68] -> MsT[s][l]
  __shared__ float dts[CHUNKL], acs[CHUNKL];
  const int tid = threadIdx.x;
  const int rbase = b*LSEQ + c*CHUNKL;
  if (tid < CHUNKL) dts[tid] = dt[(size_t)(rbase + tid)*NHEADS + hh];
  __syncthreads();
  if (tid == 0) {
    float Aval = -expf(A_log[hh]);
    float s = 0.f;
    for (int l = 0; l < CHUNKL; l++) { s += dts[l]*Aval; acs[l] = s; }
  }
  for (int i = tid; i < 16384; i += 256) {
    int n = i & 127, l = i >> 7;
    size_t g = (size_t)(rbase + l)*256;
    R2[n*132 + l] = b2f(bcb[g + n]);         // B
    R1[n*132 + l] = b2f(bcb[g + 128 + n]);   // C
  }
  __syncthreads();
  const int tx = tid & 15, ty = tid >> 4;
  const int l0 = ty*8, s0 = tx*8, p0 = tx*4;
  // phase 1: G[l][s] = sum_n C[l][n]*B[s][n]
  float G[8][8];
  #pragma unroll
  for (int i = 0; i < 8; i++)
    #pragma unroll
    for (int j = 0; j < 8; j++) G[i][j] = 0.f;
  for (int n = 0; n < 128; n++) {
    float cl[8], bs[8];
    *(float4*)&cl[0] = *(const float4*)&R1[n*132 + l0];
    *(float4*)&cl[4] = *(const float4*)&R1[n*132 + l0 + 4];
    *(float4*)&bs[0] = *(const float4*)&R2[n*132 + s0];
    *(float4*)&bs[4] = *(const float4*)&R2[n*132 + s0 + 4];
    #pragma unroll
    for (int i = 0; i < 8; i++)
      #pragma unroll
      for (int j = 0; j < 8; j++) G[i][j] = fmaf(cl[i], bs[j], G[i][j]);
  }
  __syncthreads();
  // phase 2: load PT (P transposed) over BsT
  for (int i = tid; i < 8192; i += 256) {
    int n = i & 127, p = i >> 7;
    R2[n*68 + p] = b2f(S[(size_t)((b*NCHUNK + c)*NHEADS + hh)*8192 + p*128 + n]);
  }
  __syncthreads();
  // phase 3: Y_off[l][p] = exp(acs[l]) * sum_n C[l][n] * P[p][n]
  float acc[8][4];
  #pragma unroll
  for (int i = 0; i < 8; i++) { acc[i][0]=0.f; acc[i][1]=0.f; acc[i][2]=0.f; acc[i][3]=0.f; }
  for (int n = 0; n < 128; n++) {
    float cl[8];
    *(float4*)&cl[0] = *(const float4*)&R1[n*132 + l0];
    *(float4*)&cl[4] = *(const float4*)&R1[n*132 + l0 + 4];
    float4 pv = *(const float4*)&R2[n*68 + p0];
    #pragma unroll
    for (int i = 0; i < 8; i++) {
      acc[i][0] = fmaf(cl[i], pv.x, acc[i][0]);
      acc[i][1] = fmaf(cl[i], pv.y, acc[i][1]);
      acc[i][2] = fmaf(cl[i], pv.z, acc[i][2]);
      acc[i][3] = fmaf(cl[i], pv.w, acc[i][3]);
    }
  }
  #pragma unroll
  for (int i = 0; i < 8; i++) {
    float e = expf(acs[l0 + i]);
    acc[i][0] *= e; acc[i][1] *= e; acc[i][2] *= e; acc[i][3] *= e;
  }
  __syncthreads();
  // phase 4: MsT[s][l] = (l>=s) ? G*exp(acs[l]-acs[s])*dt[s] : 0 ; load raw Xs
  #pragma unroll
  for (int i = 0; i < 8; i++) {
    int l = l0 + i;
    float al = acs[l];
    #pragma unroll
    for (int j = 0; j < 8; j++) {
      int sI = s0 + j;
      float m = (l >= sI) ? G[i][j] * expf(al - acs[sI]) * dts[sI] : 0.f;
      R2[sI*132 + l] = m;
    }
  }
  for (int i = tid; i < 8192; i += 256) {
    int p = i & 63, l = i >> 6;
    R1[l*64 + p] = b2f(xs[(size_t)(rbase + l)*DINNER + hh*HEADDIM + p]);
  }
  __syncthreads();
  // phase 5: Y_diag[l][p] += sum_s M[l][s]*xs[s][p]
  for (int s = 0; s < 128; s++) {
    float ml[8];
    *(float4*)&ml[0] = *(const float4*)&R2[s*132 + l0];
    *(float4*)&ml[4] = *(const float4*)&R2[s*132 + l0 + 4];
    float4 xv = *(const float4*)&R1[s*64 + p0];
    #pragma unroll
    for (int i = 0; i < 8; i++) {
      acc[i][0] = fmaf(ml[i], xv.x, acc[i][0]);
      acc[i][1] = fmaf(ml[i], xv.y, acc[i][1]);
      acc[i][2] = fmaf(ml[i], xv.z, acc[i][2]);
      acc[i][3] = fmaf(ml[i], xv.w, acc[i][3]);
    }
  }
  const float Dh = Dvec[hh];
  #pragma unroll
  for (int i = 0; i < 8; i++) {
    #pragma unroll
    for (int j = 0; j < 4; j++) acc[i][j] = fmaf(Dh, R1[(l0+i)*64 + p0 + j], acc[i][j]);
    ushort4 ov;
    ov.x = f2b(acc[i][0]); ov.y = f2b(acc[i][1]);
    ov.z = f2b(acc[i][2]); ov.w = f2b(acc[i][3]);
    *(ushort4*)&y[(size_t)(rbase + l0 + i)*DINNER + hh*HEADDIM + p0] = ov;
  }
}

// ---------------- gated RMSNorm (in place on y, bf16) ----------------
__global__ __launch_bounds__(256) void rmsnorm_kernel(ushort* __restrict__ y,
    const ushort* __restrict__ z, const float* __restrict__ nw)
{
  const int row = blockIdx.x;
  const int t = threadIdx.x;
  ushort* yr = y + (size_t)row*DINNER;
  const ushort* zr = z + (size_t)row*DINNER;
  float v[8];
  float ss = 0.f;
  #pragma unroll
  for (int i = 0; i < 8; i++) {
    int c = t + i*256;
    float zz = b2f(zr[c]);
    float g = b2f(yr[c]) * (zz / (1.f + expf(-zz)));
    v[i] = g;
    ss += g*g;
  }
  #pragma unroll
  for (int o = 32; o > 0; o >>= 1) ss += __shfl_down(ss, o, 64);
  __shared__ float red[4];
  if ((t & 63) == 0) red[t >> 6] = ss;
  __syncthreads();
  float scale = rsqrtf((red[0]+red[1]+red[2]+red[3]) * (1.f/DINNER) + 1e-5f);
  #pragma unroll
  for (int i = 0; i < 8; i++) {
    int c = t + i*256;
    yr[c] = f2b(v[i]*scale*nw[c]);
  }
}

// ---------------- out_proj GEMM + residual (fp32 out) ----------------
__global__ __launch_bounds__(256) void gemm_outproj_kernel(
    const ushort* __restrict__ A, const float* __restrict__ W,
    const float* __restrict__ x, float* __restrict__ out)
{
  __shared__ float As[16][132];
  __shared__ float Bs[16][132];
  const int tid = threadIdx.x;
  const int tx = tid & 15, ty = tid >> 4;
  const int m0 = blockIdx.x * 128;
  const int n0 = blockIdx.y * 128;
  float acc[8][8];
  #pragma unroll
  for (int i = 0; i < 8; i++)
    #pragma unroll
    for (int j = 0; j < 8; j++) acc[i][j] = 0.f;
  for (int k0 = 0; k0 < DINNER; k0 += 16) {
    #pragma unroll
    for (int u = 0; u < 2; u++) {
      int idx = tid + u*256;
      int r = idx >> 2;
      int kv = (idx & 3) << 2;
      ushort4 av = *(const ushort4*)(A + (size_t)(m0 + r)*DINNER + k0 + kv);
      As[kv+0][r] = b2f(av.x); As[kv+1][r] = b2f(av.y);
      As[kv+2][r] = b2f(av.z); As[kv+3][r] = b2f(av.w);
      float4 bv = *(const float4*)(W + (size_t)(n0 + r)*DINNER + k0 + kv);
      Bs[kv+0][r] = bv.x; Bs[kv+1][r] = bv.y; Bs[kv+2][r] = bv.z; Bs[kv+3][r] = bv.w;
    }
    __syncthreads();
    for (int k = 0; k < 16; k++) {
      float a[8], bb[8];
      *(float4*)&a[0]  = *(const float4*)&As[k][ty*8];
      *(float4*)&a[4]  = *(const float4*)&As[k][ty*8+4];
      *(float4*)&bb[0] = *(const float4*)&Bs[k][tx*8];
      *(float4*)&bb[4] = *(const float4*)&Bs[k][tx*8+4];
      #pragma unroll
      for (int i = 0; i < 8; i++)
        #pragma unroll
        for (int j = 0; j < 8; j++) acc[i][j] = fmaf(a[i], bb[j], acc[i][j]);
    }
    __syncthreads();
  }
  #pragma unroll
  for (int i = 0; i < 8; i++) {
    int row = m0 + ty*8 + i;
    #pragma unroll
    for (int j = 0; j < 8; j++) {
      int cc = n0 + tx*8 + j;
      out[(size_t)row*DMODEL + cc] = acc[i][j] + x[(size_t)row*DMODEL + cc];
    }
  }
}

extern "C" void kernel_launch(void* const* d_in, const int* in_sizes, int n_in,
                              void* d_out, int out_size, void* d_ws, size_t ws_size,
                              hipStream_t stream)
{
  const float* x    = (const float*)d_in[0];
  const float* lnw  = (const float*)d_in[1];
  const float* lnb  = (const float*)d_in[2];
  const float* win  = (const float*)d_in[3];
  const float* cw   = (const float*)d_in[4];
  const float* cb   = (const float*)d_in[5];
  const float* dtb  = (const float*)d_in[6];
  const float* alog = (const float*)d_in[7];
  const float* dvec = (const float*)d_in[8];
  const float* nw   = (const float*)d_in[9];
  const float* wout = (const float*)d_in[10];
  float* out = (float*)d_out;
  char* ws = (char*)d_ws;
  (void)in_sizes; (void)n_in; (void)out_size;

  if (ws_size < B_END) return;  // workspace too small: fail cleanly, don't fault

  ushort* zb   = (ushort*)(ws + B_Z);
  ushort* xbcb = (ushort*)(ws + B_XBC);
  float*  dtr  = (float*) (ws + B_DT);
  ushort* xsb  = (ushort*)(ws + B_XS);
  ushort* bcb  = (ushort*)(ws + B_BC);
  ushort* yb   = (ushort*)(ws + B_Y);
  float*  asum = (float*) (ws + B_ASUM);
  ushort* Sb   = xbcb;               // aliases xbc (dead after conv)
  ushort* hb   = yb;                 // aliases y  (y born after h dies)

  hipLaunchKernelGGL(ln_kernel, dim3(ROWS), dim3(256), 0, stream, x, lnw, lnb, hb);
  hipLaunchKernelGGL(gemm_inproj_kernel, dim3(64, 35), dim3(256), 0, stream, hb, win, zb, xbcb, dtr);
  hipLaunchKernelGGL(dt_kernel, dim3(ROWS*NHEADS/256), dim3(256), 0, stream, dtr, dtb);
  hipLaunchKernelGGL(conv_kernel, dim3(9, ROWS), dim3(256), 0, stream, xbcb, cw, cb, xsb, bcb);
  hipLaunchKernelGGL(states_kernel, dim3(NHEADS, NCHUNK, BATCH), dim3(256), 0, stream,
                     xsb, bcb, dtr, alog, Sb, asum);
  hipLaunchKernelGGL(scan_kernel, dim3(NHEADS, BATCH), dim3(256), 0, stream, Sb, asum);
  hipLaunchKernelGGL(yssd_kernel, dim3(NHEADS, NCHUNK, BATCH), dim3(256), 0, stream,
                     xsb, bcb, dtr, alog, dvec, Sb, yb);
  hipLaunchKernelGGL(rmsnorm_kernel, dim3(ROWS), dim3(256), 0, stream, yb, zb, nw);
  hipLaunchKernelGGL(gemm_outproj_kernel, dim3(64, 8), dim3(256), 0, stream, yb, wout, x, out);
}

// Round 3
// 946.179 us; speedup vs baseline: 2.0386x; 2.0386x over previous
//
#include <hip/hip_runtime.h>
#include <math.h>

#define BATCH   4
#define LSEQ    2048
#define DMODEL  1024
#define DSTATE  128
#define HEADDIM 64
#define DINNER  2048
#define NHEADS  32
#define CONVCH  2304
#define DINPROJ 4384
#define NPAD    4480
#define CHUNKL  128
#define NCHUNK  16
#define ROWS    (BATCH*LSEQ)

// ---------------- workspace layout (BYTE offsets) ----------------
#define B_Z     ((size_t)0)                              // ROWS*DINNER bf16
#define B_XBC   (B_Z   + (size_t)ROWS*DINNER*2)          // ROWS*CONVCH bf16; S aliases first 33.55MB; Wout bf16 aliases tail 4.19MB
#define B_DT    (B_XBC + (size_t)ROWS*CONVCH*2)          // ROWS*NHEADS fp32
#define B_XS    (B_DT  + (size_t)ROWS*NHEADS*4)          // ROWS*DINNER bf16
#define B_BC    (B_XS  + (size_t)ROWS*DINNER*2)          // ROWS*256 bf16
#define B_Y     (B_BC  + (size_t)ROWS*256*2)             // ROWS*DINNER bf16; h bf16 aliases [0,16.8MB); Win bf16 aliases [16.8MB,26MB)
#define B_ASUM  (B_Y   + (size_t)ROWS*DINNER*2)          // BATCH*NCHUNK*NHEADS fp32
#define B_END   (B_ASUM + (size_t)BATCH*NCHUNK*NHEADS*4) // ~137 MB total

typedef __attribute__((ext_vector_type(8))) short bf16x8;
typedef __attribute__((ext_vector_type(4))) float f32x4;

__device__ __forceinline__ float b2f(ushort u) {
  union { uint32_t i; float f; } v; v.i = ((uint32_t)u) << 16; return v.f;
}
__device__ __forceinline__ ushort f2b(float f) {
  union { float f; uint32_t i; } v; v.f = f;
  uint32_t r = (v.i + 0x7FFFu + ((v.i >> 16) & 1u)) >> 16;
  return (ushort)r;
}

__device__ __forceinline__ void async_ld16(const void* g, void* l) {
  __builtin_amdgcn_global_load_lds(
      (const __attribute__((address_space(1))) unsigned int*)g,
      (__attribute__((address_space(3))) unsigned int*)l, 16, 0, 0);
}

// ---------------- weight fp32 -> bf16 converters ----------------
__global__ __launch_bounds__(256) void convert_win_kernel(const float* __restrict__ W,
                                                          ushort* __restrict__ Wb)
{
  size_t i = (size_t)blockIdx.x*256 + threadIdx.x;  // grid covers NPAD*DMODEL
  Wb[i] = (i < (size_t)DINPROJ*DMODEL) ? f2b(W[i]) : (ushort)0;
}

__global__ __launch_bounds__(256) void convert_wout_kernel(const float* __restrict__ W,
                                                           ushort* __restrict__ Wb)
{
  size_t i = (size_t)blockIdx.x*256 + threadIdx.x;  // DMODEL*DINNER
  Wb[i] = f2b(W[i]);
}

// ---------------- LayerNorm -> h (bf16) ----------------
__global__ __launch_bounds__(256) void ln_kernel(const float* __restrict__ x,
    const float* __restrict__ w, const float* __restrict__ bias, ushort* __restrict__ h)
{
  const int row = blockIdx.x;
  const int t = threadIdx.x;
  const float* xr = x + (size_t)row * DMODEL;
  float v[4];
  float s = 0.f;
  #pragma unroll
  for (int i = 0; i < 4; i++) { v[i] = xr[t + i*256]; s += v[i]; }
  __shared__ float red[4];
  #pragma unroll
  for (int o = 32; o > 0; o >>= 1) s += __shfl_down(s, o, 64);
  if ((t & 63) == 0) red[t >> 6] = s;
  __syncthreads();
  float mean = (red[0]+red[1]+red[2]+red[3]) * (1.f/DMODEL);
  float vs = 0.f;
  #pragma unroll
  for (int i = 0; i < 4; i++) { float d = v[i]-mean; vs += d*d; }
  #pragma unroll
  for (int o = 32; o > 0; o >>= 1) vs += __shfl_down(vs, o, 64);
  __syncthreads();
  if ((t & 63) == 0) red[t >> 6] = vs;
  __syncthreads();
  float rstd = rsqrtf((red[0]+red[1]+red[2]+red[3]) * (1.f/DMODEL) + 1e-5f);
  ushort* hr = h + (size_t)row * DMODEL;
  #pragma unroll
  for (int i = 0; i < 4; i++) {
    int c = t + i*256;
    hr[c] = f2b((v[i]-mean)*rstd*w[c] + bias[c]);
  }
}

// ---------------- in_proj MFMA GEMM: [8192][4480] = h[8192][1024] @ Wpad[4480][1024]^T ----------------
__global__ __launch_bounds__(256) void gemm_inproj_mfma(const ushort* __restrict__ A,
    const ushort* __restrict__ W, ushort* __restrict__ z, ushort* __restrict__ xbc,
    float* __restrict__ dtr)
{
  constexpr int K = DMODEL;
  __shared__ ushort lA[128*32];
  __shared__ ushort lB[128*32];
  const int tid = threadIdx.x;
  const int lane = tid & 63;
  const int w = tid >> 6;
  const int m0 = blockIdx.x * 128;
  const int n0 = blockIdx.y * 128;
  const int wm = (w & 1) * 64;
  const int wn = (w >> 1) * 64;
  f32x4 acc[4][4];
  #pragma unroll
  for (int i = 0; i < 4; i++)
    #pragma unroll
    for (int j = 0; j < 4; j++) acc[i][j] = (f32x4)(0.f);

  for (int k0 = 0; k0 < K; k0 += 32) {
    __syncthreads();
    #pragma unroll
    for (int is = 0; is < 2; is++) {
      int c = w*128 + is*64 + lane;
      int row = c >> 2, cb = c & 3;
      async_ld16(A + (size_t)(m0 + row)*K + k0 + cb*8, lA + (size_t)(w*128 + is*64)*8);
      async_ld16(W + (size_t)(n0 + row)*K + k0 + cb*8, lB + (size_t)(w*128 + is*64)*8);
    }
    __syncthreads();
    bf16x8 af[4], bfr[4];
    #pragma unroll
    for (int i = 0; i < 4; i++)
      af[i] = *(const bf16x8*)&lA[(wm + i*16 + (lane & 15))*32 + (lane >> 4)*8];
    #pragma unroll
    for (int j = 0; j < 4; j++)
      bfr[j] = *(const bf16x8*)&lB[(wn + j*16 + (lane & 15))*32 + (lane >> 4)*8];
    #pragma unroll
    for (int i = 0; i < 4; i++)
      #pragma unroll
      for (int j = 0; j < 4; j++)
        acc[i][j] = __builtin_amdgcn_mfma_f32_16x16x32_bf16(af[i], bfr[j], acc[i][j], 0, 0, 0);
  }

  const int col_l = lane & 15;
  const int row_l = (lane >> 4) * 4;
  #pragma unroll
  for (int i = 0; i < 4; i++) {
    #pragma unroll
    for (int j = 0; j < 4; j++) {
      int gn = n0 + wn + j*16 + col_l;
      #pragma unroll
      for (int r = 0; r < 4; r++) {
        int gm = m0 + wm + i*16 + row_l + r;
        float v = acc[i][j][r];
        if (gn < DINNER)                z[(size_t)gm*DINNER + gn] = f2b(v);
        else if (gn < DINNER + CONVCH)  xbc[(size_t)gm*CONVCH + (gn - DINNER)] = f2b(v);
        else if (gn < DINPROJ)          dtr[(size_t)gm*NHEADS + (gn - DINNER - CONVCH)] = v;
      }
    }
  }
}

// ---------------- out_proj MFMA GEMM + residual: out[8192][1024] = y[8192][2048] @ Wout[1024][2048]^T + x ----------------
__global__ __launch_bounds__(256) void gemm_outproj_mfma(const ushort* __restrict__ A,
    const ushort* __restrict__ W, const float* __restrict__ x, float* __restrict__ out)
{
  constexpr int K = DINNER;
  __shared__ ushort lA[128*32];
  __shared__ ushort lB[128*32];
  const int tid = threadIdx.x;
  const int lane = tid & 63;
  const int w = tid >> 6;
  const int m0 = blockIdx.x * 128;
  const int n0 = blockIdx.y * 128;
  const int wm = (w & 1) * 64;
  const int wn = (w >> 1) * 64;
  f32x4 acc[4][4];
  #pragma unroll
  for (int i = 0; i < 4; i++)
    #pragma unroll
    for (int j = 0; j < 4; j++) acc[i][j] = (f32x4)(0.f);

  for (int k0 = 0; k0 < K; k0 += 32) {
    __syncthreads();
    #pragma unroll
    for (int is = 0; is < 2; is++) {
      int c = w*128 + is*64 + lane;
      int row = c >> 2, cb = c & 3;
      async_ld16(A + (size_t)(m0 + row)*K + k0 + cb*8, lA + (size_t)(w*128 + is*64)*8);
      async_ld16(W + (size_t)(n0 + row)*K + k0 + cb*8, lB + (size_t)(w*128 + is*64)*8);
    }
    __syncthreads();
    bf16x8 af[4], bfr[4];
    #pragma unroll
    for (int i = 0; i < 4; i++)
      af[i] = *(const bf16x8*)&lA[(wm + i*16 + (lane & 15))*32 + (lane >> 4)*8];
    #pragma unroll
    for (int j = 0; j < 4; j++)
      bfr[j] = *(const bf16x8*)&lB[(wn + j*16 + (lane & 15))*32 + (lane >> 4)*8];
    #pragma unroll
    for (int i = 0; i < 4; i++)
      #pragma unroll
      for (int j = 0; j < 4; j++)
        acc[i][j] = __builtin_amdgcn_mfma_f32_16x16x32_bf16(af[i], bfr[j], acc[i][j], 0, 0, 0);
  }

  const int col_l = lane & 15;
  const int row_l = (lane >> 4) * 4;
  #pragma unroll
  for (int i = 0; i < 4; i++) {
    #pragma unroll
    for (int j = 0; j < 4; j++) {
      int gn = n0 + wn + j*16 + col_l;
      #pragma unroll
      for (int r = 0; r < 4; r++) {
        int gm = m0 + wm + i*16 + row_l + r;
        out[(size_t)gm*DMODEL + gn] = acc[i][j][r] + x[(size_t)gm*DMODEL + gn];
      }
    }
  }
}

// ---------------- dt = softplus(dt_raw + bias), in place (fp32) ----------------
__global__ __launch_bounds__(256) void dt_kernel(float* __restrict__ dtr, const float* __restrict__ dtb)
{
  int i = blockIdx.x*256 + threadIdx.x;
  float v = dtr[i] + dtb[i & (NHEADS-1)];
  dtr[i] = (v > 20.f) ? v : log1pf(expf(v));
}

// ---------------- causal conv4 + SiLU, split xs / BC (bf16 in/out) ----------------
__global__ __launch_bounds__(256) void conv_kernel(const ushort* __restrict__ xbc,
    const float* __restrict__ cw, const float* __restrict__ cb,
    ushort* __restrict__ xs, ushort* __restrict__ bcb)
{
  int ch  = blockIdx.x*256 + threadIdx.x;   // 0..2303
  int row = blockIdx.y;                     // b*LSEQ + l
  int l = row & (LSEQ-1);
  float acc = cb[ch];
  #pragma unroll
  for (int k = 0; k < 4; k++) {
    int t = l + k - 3;
    if (t >= 0) acc = fmaf(b2f(xbc[(size_t)(row + k - 3)*CONVCH + ch]), cw[ch*4 + k], acc);
  }
  float v = acc / (1.f + expf(-acc));
  if (ch < DINNER) xs[(size_t)row*DINNER + ch] = f2b(v);
  else             bcb[(size_t)row*256 + (ch - DINNER)] = f2b(v);
}

// ---------------- per-chunk states: S[b,c,h,p,n] (bf16 out) ----------------
__global__ __launch_bounds__(256) void states_kernel(
    const ushort* __restrict__ xs, const ushort* __restrict__ bcb, const float* __restrict__ dt,
    const float* __restrict__ A_log, ushort* __restrict__ S, float* __restrict__ asum)
{
  const int hh = blockIdx.x, c = blockIdx.y, b = blockIdx.z;
  __shared__ float Bsm[CHUNKL][DSTATE];   // 64 KB
  __shared__ float Xsm[CHUNKL][HEADDIM];  // 32 KB
  __shared__ float dts[CHUNKL], acs[CHUNKL];
  const int tid = threadIdx.x;
  const int rbase = b*LSEQ + c*CHUNKL;
  if (tid < CHUNKL) dts[tid] = dt[(size_t)(rbase + tid)*NHEADS + hh];
  __syncthreads();
  if (tid == 0) {
    float Aval = -expf(A_log[hh]);
    float s = 0.f;
    for (int l = 0; l < CHUNKL; l++) { s += dts[l]*Aval; acs[l] = s; }
    asum[(b*NCHUNK + c)*NHEADS + hh] = s;
  }
  __syncthreads();
  const float alast = acs[CHUNKL-1];
  for (int i = tid; i < CHUNKL*DSTATE; i += 256) {
    int l = i >> 7, n = i & 127;
    Bsm[l][n] = b2f(bcb[(size_t)(rbase + l)*256 + n]);
  }
  for (int i = tid; i < CHUNKL*HEADDIM; i += 256) {
    int l = i >> 6, p = i & 63;
    Xsm[l][p] = b2f(xs[(size_t)(rbase + l)*DINNER + hh*HEADDIM + p]) * dts[l] * expf(alast - acs[l]);
  }
  __syncthreads();
  const int n0 = (tid & 31) * 4, p0 = (tid >> 5) * 8;
  float acc[8][4];
  #pragma unroll
  for (int i = 0; i < 8; i++) { acc[i][0]=0.f; acc[i][1]=0.f; acc[i][2]=0.f; acc[i][3]=0.f; }
  for (int l = 0; l < CHUNKL; l++) {
    float4 bv = *(const float4*)&Bsm[l][n0];
    float xv[8];
    *(float4*)&xv[0] = *(const float4*)&Xsm[l][p0];
    *(float4*)&xv[4] = *(const float4*)&Xsm[l][p0+4];
    #pragma unroll
    for (int i = 0; i < 8; i++) {
      acc[i][0] = fmaf(xv[i], bv.x, acc[i][0]);
      acc[i][1] = fmaf(xv[i], bv.y, acc[i][1]);
      acc[i][2] = fmaf(xv[i], bv.z, acc[i][2]);
      acc[i][3] = fmaf(xv[i], bv.w, acc[i][3]);
    }
  }
  ushort* Sp = S + (size_t)((b*NCHUNK + c)*NHEADS + hh) * (HEADDIM*DSTATE);
  #pragma unroll
  for (int i = 0; i < 8; i++) {
    ushort4 sv;
    sv.x = f2b(acc[i][0]); sv.y = f2b(acc[i][1]);
    sv.z = f2b(acc[i][2]); sv.w = f2b(acc[i][3]);
    *(ushort4*)&Sp[(p0+i)*DSTATE + n0] = sv;
  }
}

// ---------------- inter-chunk scan (in place: S becomes prev_states P), fp32 carry ----------------
__global__ __launch_bounds__(256) void scan_kernel(ushort* __restrict__ S, const float* __restrict__ asum)
{
  const int hh = blockIdx.x, b = blockIdx.y;
  const int tid = threadIdx.x;
  float carry[32];
  #pragma unroll
  for (int i = 0; i < 32; i++) carry[i] = 0.f;
  for (int c = 0; c < NCHUNK; c++) {
    ushort* Sp = S + (size_t)((b*NCHUNK + c)*NHEADS + hh) * 8192;
    float dec = expf(asum[(b*NCHUNK + c)*NHEADS + hh]);
    #pragma unroll
    for (int i = 0; i < 32; i++) {
      float sv = b2f(Sp[tid + i*256]);
      Sp[tid + i*256] = f2b(carry[i]);
      carry[i] = fmaf(dec, carry[i], sv);
    }
  }
}

// ---------------- Y = Y_diag + Y_off + D*xs (bf16 out) ----------------
__global__ __launch_bounds__(256) void yssd_kernel(
    const ushort* __restrict__ xs, const ushort* __restrict__ bcb, const float* __restrict__ dt,
    const float* __restrict__ A_log, const float* __restrict__ Dvec,
    const ushort* __restrict__ S, ushort* __restrict__ y)
{
  const int hh = blockIdx.x, c = blockIdx.y, b = blockIdx.z;
  __shared__ float R1[128*132];  // CsT[n][l] -> Xs[s][64]
  __shared__ float R2[128*132];  // BsT[n][s] -> PT[n][68] -> MsT[s][l]
  __shared__ float dts[CHUNKL], acs[CHUNKL];
  const int tid = threadIdx.x;
  const int rbase = b*LSEQ + c*CHUNKL;
  if (tid < CHUNKL) dts[tid] = dt[(size_t)(rbase + tid)*NHEADS + hh];
  __syncthreads();
  if (tid == 0) {
    float Aval = -expf(A_log[hh]);
    float s = 0.f;
    for (int l = 0; l < CHUNKL; l++) { s += dts[l]*Aval; acs[l] = s; }
  }
  for (int i = tid; i < 16384; i += 256) {
    int n = i & 127, l = i >> 7;
    size_t g = (size_t)(rbase + l)*256;
    R2[n*132 + l] = b2f(bcb[g + n]);         // B
    R1[n*132 + l] = b2f(bcb[g + 128 + n]);   // C
  }
  __syncthreads();
  const int tx = tid & 15, ty = tid >> 4;
  const int l0 = ty*8, s0 = tx*8, p0 = tx*4;
  // phase 1: G[l][s] = sum_n C[l][n]*B[s][n]
  float G[8][8];
  #pragma unroll
  for (int i = 0; i < 8; i++)
    #pragma unroll
    for (int j = 0; j < 8; j++) G[i][j] = 0.f;
  for (int n = 0; n < 128; n++) {
    float cl[8], bs[8];
    *(float4*)&cl[0] = *(const float4*)&R1[n*132 + l0];
    *(float4*)&cl[4] = *(const float4*)&R1[n*132 + l0 + 4];
    *(float4*)&bs[0] = *(const float4*)&R2[n*132 + s0];
    *(float4*)&bs[4] = *(const float4*)&R2[n*132 + s0 + 4];
    #pragma unroll
    for (int i = 0; i < 8; i++)
      #pragma unroll
      for (int j = 0; j < 8; j++) G[i][j] = fmaf(cl[i], bs[j], G[i][j]);
  }
  __syncthreads();
  // phase 2: load PT (P transposed) over BsT
  for (int i = tid; i < 8192; i += 256) {
    int n = i & 127, p = i >> 7;
    R2[n*68 + p] = b2f(S[(size_t)((b*NCHUNK + c)*NHEADS + hh)*8192 + p*128 + n]);
  }
  __syncthreads();
  // phase 3: Y_off[l][p] = exp(acs[l]) * sum_n C[l][n] * P[p][n]
  float acc[8][4];
  #pragma unroll
  for (int i = 0; i < 8; i++) { acc[i][0]=0.f; acc[i][1]=0.f; acc[i][2]=0.f; acc[i][3]=0.f; }
  for (int n = 0; n < 128; n++) {
    float cl[8];
    *(float4*)&cl[0] = *(const float4*)&R1[n*132 + l0];
    *(float4*)&cl[4] = *(const float4*)&R1[n*132 + l0 + 4];
    float4 pv = *(const float4*)&R2[n*68 + p0];
    #pragma unroll
    for (int i = 0; i < 8; i++) {
      acc[i][0] = fmaf(cl[i], pv.x, acc[i][0]);
      acc[i][1] = fmaf(cl[i], pv.y, acc[i][1]);
      acc[i][2] = fmaf(cl[i], pv.z, acc[i][2]);
      acc[i][3] = fmaf(cl[i], pv.w, acc[i][3]);
    }
  }
  #pragma unroll
  for (int i = 0; i < 8; i++) {
    float e = expf(acs[l0 + i]);
    acc[i][0] *= e; acc[i][1] *= e; acc[i][2] *= e; acc[i][3] *= e;
  }
  __syncthreads();
  // phase 4: MsT[s][l] = (l>=s) ? G*exp(acs[l]-acs[s])*dt[s] : 0 ; load raw Xs
  #pragma unroll
  for (int i = 0; i < 8; i++) {
    int l = l0 + i;
    float al = acs[l];
    #pragma unroll
    for (int j = 0; j < 8; j++) {
      int sI = s0 + j;
      float m = (l >= sI) ? G[i][j] * expf(al - acs[sI]) * dts[sI] : 0.f;
      R2[sI*132 + l] = m;
    }
  }
  for (int i = tid; i < 8192; i += 256) {
    int p = i & 63, l = i >> 6;
    R1[l*64 + p] = b2f(xs[(size_t)(rbase + l)*DINNER + hh*HEADDIM + p]);
  }
  __syncthreads();
  // phase 5: Y_diag[l][p] += sum_s M[l][s]*xs[s][p]
  for (int s = 0; s < 128; s++) {
    float ml[8];
    *(float4*)&ml[0] = *(const float4*)&R2[s*132 + l0];
    *(float4*)&ml[4] = *(const float4*)&R2[s*132 + l0 + 4];
    float4 xv = *(const float4*)&R1[s*64 + p0];
    #pragma unroll
    for (int i = 0; i < 8; i++) {
      acc[i][0] = fmaf(ml[i], xv.x, acc[i][0]);
      acc[i][1] = fmaf(ml[i], xv.y, acc[i][1]);
      acc[i][2] = fmaf(ml[i], xv.z, acc[i][2]);
      acc[i][3] = fmaf(ml[i], xv.w, acc[i][3]);
    }
  }
  const float Dh = Dvec[hh];
  #pragma unroll
  for (int i = 0; i < 8; i++) {
    #pragma unroll
    for (int j = 0; j < 4; j++) acc[i][j] = fmaf(Dh, R1[(l0+i)*64 + p0 + j], acc[i][j]);
    ushort4 ov;
    ov.x = f2b(acc[i][0]); ov.y = f2b(acc[i][1]);
    ov.z = f2b(acc[i][2]); ov.w = f2b(acc[i][3]);
    *(ushort4*)&y[(size_t)(rbase + l0 + i)*DINNER + hh*HEADDIM + p0] = ov;
  }
}

// ---------------- gated RMSNorm (in place on y, bf16) ----------------
__global__ __launch_bounds__(256) void rmsnorm_kernel(ushort* __restrict__ y,
    const ushort* __restrict__ z, const float* __restrict__ nw)
{
  const int row = blockIdx.x;
  const int t = threadIdx.x;
  ushort* yr = y + (size_t)row*DINNER;
  const ushort* zr = z + (size_t)row*DINNER;
  float v[8];
  float ss = 0.f;
  #pragma unroll
  for (int i = 0; i < 8; i++) {
    int c = t + i*256;
    float zz = b2f(zr[c]);
    float g = b2f(yr[c]) * (zz / (1.f + expf(-zz)));
    v[i] = g;
    ss += g*g;
  }
  #pragma unroll
  for (int o = 32; o > 0; o >>= 1) ss += __shfl_down(ss, o, 64);
  __shared__ float red[4];
  if ((t & 63) == 0) red[t >> 6] = ss;
  __syncthreads();
  float scale = rsqrtf((red[0]+red[1]+red[2]+red[3]) * (1.f/DINNER) + 1e-5f);
  #pragma unroll
  for (int i = 0; i < 8; i++) {
    int c = t + i*256;
    yr[c] = f2b(v[i]*scale*nw[c]);
  }
}

extern "C" void kernel_launch(void* const* d_in, const int* in_sizes, int n_in,
                              void* d_out, int out_size, void* d_ws, size_t ws_size,
                              hipStream_t stream)
{
  const float* x    = (const float*)d_in[0];
  const float* lnw  = (const float*)d_in[1];
  const float* lnb  = (const float*)d_in[2];
  const float* win  = (const float*)d_in[3];
  const float* cw   = (const float*)d_in[4];
  const float* cb   = (const float*)d_in[5];
  const float* dtb  = (const float*)d_in[6];
  const float* alog = (const float*)d_in[7];
  const float* dvec = (const float*)d_in[8];
  const float* nw   = (const float*)d_in[9];
  const float* wout = (const float*)d_in[10];
  float* out = (float*)d_out;
  char* ws = (char*)d_ws;
  (void)in_sizes; (void)n_in; (void)out_size;

  if (ws_size < B_END) return;  // workspace too small: fail cleanly, don't fault

  ushort* zb   = (ushort*)(ws + B_Z);
  ushort* xbcb = (ushort*)(ws + B_XBC);
  float*  dtr  = (float*) (ws + B_DT);
  ushort* xsb  = (ushort*)(ws + B_XS);
  ushort* bcb  = (ushort*)(ws + B_BC);
  ushort* yb   = (ushort*)(ws + B_Y);
  float*  asum = (float*) (ws + B_ASUM);
  ushort* Sb   = xbcb;                                        // aliases xbc (dead after conv)
  ushort* hb   = yb;                                          // aliases y[0 : 16.8MB]
  ushort* winB = (ushort*)(ws + B_Y + (size_t)ROWS*DMODEL*2); // aliases y[16.8MB : 26MB]
  ushort* woutB= (ushort*)(ws + B_XBC + (size_t)BATCH*NCHUNK*NHEADS*HEADDIM*DSTATE*2); // XBC tail (4.19MB)

  hipLaunchKernelGGL(convert_win_kernel, dim3((NPAD*DMODEL)/256), dim3(256), 0, stream, win, winB);
  hipLaunchKernelGGL(ln_kernel, dim3(ROWS), dim3(256), 0, stream, x, lnw, lnb, hb);
  hipLaunchKernelGGL(gemm_inproj_mfma, dim3(64, 35), dim3(256), 0, stream, hb, winB, zb, xbcb, dtr);
  hipLaunchKernelGGL(dt_kernel, dim3(ROWS*NHEADS/256), dim3(256), 0, stream, dtr, dtb);
  hipLaunchKernelGGL(conv_kernel, dim3(9, ROWS), dim3(256), 0, stream, xbcb, cw, cb, xsb, bcb);
  hipLaunchKernelGGL(convert_wout_kernel, dim3((DMODEL*DINNER)/256), dim3(256), 0, stream, wout, woutB);
  hipLaunchKernelGGL(states_kernel, dim3(NHEADS, NCHUNK, BATCH), dim3(256), 0, stream,
                     xsb, bcb, dtr, alog, Sb, asum);
  hipLaunchKernelGGL(scan_kernel, dim3(NHEADS, BATCH), dim3(256), 0, stream, Sb, asum);
  hipLaunchKernelGGL(yssd_kernel, dim3(NHEADS, NCHUNK, BATCH), dim3(256), 0, stream,
                     xsb, bcb, dtr, alog, dvec, Sb, yb);
  hipLaunchKernelGGL(rmsnorm_kernel, dim3(ROWS), dim3(256), 0, stream, yb, zb, nw);
  hipLaunchKernelGGL(gemm_outproj_mfma, dim3(64, 8), dim3(256), 0, stream, yb, woutB, x, out);
}

// Round 4
// 660.659 us; speedup vs baseline: 2.9196x; 1.4322x over previous
//
#include <hip/hip_runtime.h>
#include <math.h>

#define BATCH   4
#define LSEQ    2048
#define DMODEL  1024
#define DSTATE  128
#define HEADDIM 64
#define DINNER  2048
#define NHEADS  32
#define CONVCH  2304
#define DINPROJ 4384
#define NPAD    4480
#define CHUNKL  128
#define NCHUNK  16
#define ROWS    (BATCH*LSEQ)

// ---------------- workspace layout (BYTE offsets) ----------------
#define B_Z     ((size_t)0)                              // ROWS*DINNER bf16
#define B_XBC   (B_Z   + (size_t)ROWS*DINNER*2)          // ROWS*CONVCH bf16; S aliases first 33.55MB; Wout bf16 aliases tail 4.19MB
#define B_DT    (B_XBC + (size_t)ROWS*CONVCH*2)          // ROWS*NHEADS fp32
#define B_XS    (B_DT  + (size_t)ROWS*NHEADS*4)          // ROWS*DINNER bf16
#define B_BC    (B_XS  + (size_t)ROWS*DINNER*2)          // ROWS*256 bf16
#define B_Y     (B_BC  + (size_t)ROWS*256*2)             // ROWS*DINNER bf16; h bf16 aliases [0,16.8MB); Win bf16 aliases [16.8MB,26MB)
#define B_ASUM  (B_Y   + (size_t)ROWS*DINNER*2)          // BATCH*NCHUNK*NHEADS fp32
#define B_END   (B_ASUM + (size_t)BATCH*NCHUNK*NHEADS*4) // ~137 MB total

typedef __attribute__((ext_vector_type(8))) short bf16x8;
typedef __attribute__((ext_vector_type(4))) float f32x4;

__device__ __forceinline__ float b2f(ushort u) {
  union { uint32_t i; float f; } v; v.i = ((uint32_t)u) << 16; return v.f;
}
__device__ __forceinline__ ushort f2b(float f) {
  union { float f; uint32_t i; } v; v.f = f;
  uint32_t r = (v.i + 0x7FFFu + ((v.i >> 16) & 1u)) >> 16;
  return (ushort)r;
}

__device__ __forceinline__ void async_ld16(const void* g, void* l) {
  __builtin_amdgcn_global_load_lds(
      (const __attribute__((address_space(1))) unsigned int*)g,
      (__attribute__((address_space(3))) unsigned int*)l, 16, 0, 0);
}

// ---------------- weight fp32 -> bf16 converters ----------------
__global__ __launch_bounds__(256) void convert_win_kernel(const float* __restrict__ W,
                                                          ushort* __restrict__ Wb)
{
  size_t i = (size_t)blockIdx.x*256 + threadIdx.x;  // grid covers NPAD*DMODEL
  Wb[i] = (i < (size_t)DINPROJ*DMODEL) ? f2b(W[i]) : (ushort)0;
}

__global__ __launch_bounds__(256) void convert_wout_kernel(const float* __restrict__ W,
                                                           ushort* __restrict__ Wb)
{
  size_t i = (size_t)blockIdx.x*256 + threadIdx.x;  // DMODEL*DINNER
  Wb[i] = f2b(W[i]);
}

// ---------------- LayerNorm -> h (bf16) ----------------
__global__ __launch_bounds__(256) void ln_kernel(const float* __restrict__ x,
    const float* __restrict__ w, const float* __restrict__ bias, ushort* __restrict__ h)
{
  const int row = blockIdx.x;
  const int t = threadIdx.x;
  const float* xr = x + (size_t)row * DMODEL;
  float v[4];
  float s = 0.f;
  #pragma unroll
  for (int i = 0; i < 4; i++) { v[i] = xr[t + i*256]; s += v[i]; }
  __shared__ float red[4];
  #pragma unroll
  for (int o = 32; o > 0; o >>= 1) s += __shfl_down(s, o, 64);
  if ((t & 63) == 0) red[t >> 6] = s;
  __syncthreads();
  float mean = (red[0]+red[1]+red[2]+red[3]) * (1.f/DMODEL);
  float vs = 0.f;
  #pragma unroll
  for (int i = 0; i < 4; i++) { float d = v[i]-mean; vs += d*d; }
  #pragma unroll
  for (int o = 32; o > 0; o >>= 1) vs += __shfl_down(vs, o, 64);
  __syncthreads();
  if ((t & 63) == 0) red[t >> 6] = vs;
  __syncthreads();
  float rstd = rsqrtf((red[0]+red[1]+red[2]+red[3]) * (1.f/DMODEL) + 1e-5f);
  ushort* hr = h + (size_t)row * DMODEL;
  #pragma unroll
  for (int i = 0; i < 4; i++) {
    int c = t + i*256;
    hr[c] = f2b((v[i]-mean)*rstd*w[c] + bias[c]);
  }
}

// ---------------- in_proj MFMA GEMM: [8192][4480] = h[8192][1024] @ Wpad[4480][1024]^T ----------------
__global__ __launch_bounds__(256) void gemm_inproj_mfma(const ushort* __restrict__ A,
    const ushort* __restrict__ W, ushort* __restrict__ z, ushort* __restrict__ xbc,
    float* __restrict__ dtr)
{
  constexpr int K = DMODEL;
  __shared__ ushort lA[128*32];
  __shared__ ushort lB[128*32];
  const int tid = threadIdx.x;
  const int lane = tid & 63;
  const int w = tid >> 6;
  const int m0 = blockIdx.x * 128;
  const int n0 = blockIdx.y * 128;
  const int wm = (w & 1) * 64;
  const int wn = (w >> 1) * 64;
  f32x4 acc[4][4];
  #pragma unroll
  for (int i = 0; i < 4; i++)
    #pragma unroll
    for (int j = 0; j < 4; j++) acc[i][j] = (f32x4)(0.f);

  for (int k0 = 0; k0 < K; k0 += 32) {
    __syncthreads();
    #pragma unroll
    for (int is = 0; is < 2; is++) {
      int c = w*128 + is*64 + lane;
      int row = c >> 2, cb = c & 3;
      async_ld16(A + (size_t)(m0 + row)*K + k0 + cb*8, lA + (size_t)(w*128 + is*64)*8);
      async_ld16(W + (size_t)(n0 + row)*K + k0 + cb*8, lB + (size_t)(w*128 + is*64)*8);
    }
    __syncthreads();
    bf16x8 af[4], bfr[4];
    #pragma unroll
    for (int i = 0; i < 4; i++)
      af[i] = *(const bf16x8*)&lA[(wm + i*16 + (lane & 15))*32 + (lane >> 4)*8];
    #pragma unroll
    for (int j = 0; j < 4; j++)
      bfr[j] = *(const bf16x8*)&lB[(wn + j*16 + (lane & 15))*32 + (lane >> 4)*8];
    #pragma unroll
    for (int i = 0; i < 4; i++)
      #pragma unroll
      for (int j = 0; j < 4; j++)
        acc[i][j] = __builtin_amdgcn_mfma_f32_16x16x32_bf16(af[i], bfr[j], acc[i][j], 0, 0, 0);
  }

  const int col_l = lane & 15;
  const int row_l = (lane >> 4) * 4;
  #pragma unroll
  for (int i = 0; i < 4; i++) {
    #pragma unroll
    for (int j = 0; j < 4; j++) {
      int gn = n0 + wn + j*16 + col_l;
      #pragma unroll
      for (int r = 0; r < 4; r++) {
        int gm = m0 + wm + i*16 + row_l + r;
        float v = acc[i][j][r];
        if (gn < DINNER)                z[(size_t)gm*DINNER + gn] = f2b(v);
        else if (gn < DINNER + CONVCH)  xbc[(size_t)gm*CONVCH + (gn - DINNER)] = f2b(v);
        else if (gn < DINPROJ)          dtr[(size_t)gm*NHEADS + (gn - DINNER - CONVCH)] = v;
      }
    }
  }
}

// ---------------- out_proj MFMA GEMM + residual ----------------
__global__ __launch_bounds__(256) void gemm_outproj_mfma(const ushort* __restrict__ A,
    const ushort* __restrict__ W, const float* __restrict__ x, float* __restrict__ out)
{
  constexpr int K = DINNER;
  __shared__ ushort lA[128*32];
  __shared__ ushort lB[128*32];
  const int tid = threadIdx.x;
  const int lane = tid & 63;
  const int w = tid >> 6;
  const int m0 = blockIdx.x * 128;
  const int n0 = blockIdx.y * 128;
  const int wm = (w & 1) * 64;
  const int wn = (w >> 1) * 64;
  f32x4 acc[4][4];
  #pragma unroll
  for (int i = 0; i < 4; i++)
    #pragma unroll
    for (int j = 0; j < 4; j++) acc[i][j] = (f32x4)(0.f);

  for (int k0 = 0; k0 < K; k0 += 32) {
    __syncthreads();
    #pragma unroll
    for (int is = 0; is < 2; is++) {
      int c = w*128 + is*64 + lane;
      int row = c >> 2, cb = c & 3;
      async_ld16(A + (size_t)(m0 + row)*K + k0 + cb*8, lA + (size_t)(w*128 + is*64)*8);
      async_ld16(W + (size_t)(n0 + row)*K + k0 + cb*8, lB + (size_t)(w*128 + is*64)*8);
    }
    __syncthreads();
    bf16x8 af[4], bfr[4];
    #pragma unroll
    for (int i = 0; i < 4; i++)
      af[i] = *(const bf16x8*)&lA[(wm + i*16 + (lane & 15))*32 + (lane >> 4)*8];
    #pragma unroll
    for (int j = 0; j < 4; j++)
      bfr[j] = *(const bf16x8*)&lB[(wn + j*16 + (lane & 15))*32 + (lane >> 4)*8];
    #pragma unroll
    for (int i = 0; i < 4; i++)
      #pragma unroll
      for (int j = 0; j < 4; j++)
        acc[i][j] = __builtin_amdgcn_mfma_f32_16x16x32_bf16(af[i], bfr[j], acc[i][j], 0, 0, 0);
  }

  const int col_l = lane & 15;
  const int row_l = (lane >> 4) * 4;
  #pragma unroll
  for (int i = 0; i < 4; i++) {
    #pragma unroll
    for (int j = 0; j < 4; j++) {
      int gn = n0 + wn + j*16 + col_l;
      #pragma unroll
      for (int r = 0; r < 4; r++) {
        int gm = m0 + wm + i*16 + row_l + r;
        out[(size_t)gm*DMODEL + gn] = acc[i][j][r] + x[(size_t)gm*DMODEL + gn];
      }
    }
  }
}

// ---------------- dt = softplus(dt_raw + bias), in place (fp32) ----------------
__global__ __launch_bounds__(256) void dt_kernel(float* __restrict__ dtr, const float* __restrict__ dtb)
{
  int i = blockIdx.x*256 + threadIdx.x;
  float v = dtr[i] + dtb[i & (NHEADS-1)];
  dtr[i] = (v > 20.f) ? v : log1pf(expf(v));
}

// ---------------- causal conv4 + SiLU, split xs / BC (bf16 in/out) ----------------
__global__ __launch_bounds__(256) void conv_kernel(const ushort* __restrict__ xbc,
    const float* __restrict__ cw, const float* __restrict__ cb,
    ushort* __restrict__ xs, ushort* __restrict__ bcb)
{
  int ch  = blockIdx.x*256 + threadIdx.x;   // 0..2303
  int row = blockIdx.y;                     // b*LSEQ + l
  int l = row & (LSEQ-1);
  float acc = cb[ch];
  #pragma unroll
  for (int k = 0; k < 4; k++) {
    int t = l + k - 3;
    if (t >= 0) acc = fmaf(b2f(xbc[(size_t)(row + k - 3)*CONVCH + ch]), cw[ch*4 + k], acc);
  }
  float v = acc / (1.f + expf(-acc));
  if (ch < DINNER) xs[(size_t)row*DINNER + ch] = f2b(v);
  else             bcb[(size_t)row*256 + (ch - DINNER)] = f2b(v);
}

// ---------------- per-chunk states: S[b,c,h,p,n] (bf16 out) ----------------
__global__ __launch_bounds__(256) void states_kernel(
    const ushort* __restrict__ xs, const ushort* __restrict__ bcb, const float* __restrict__ dt,
    const float* __restrict__ A_log, ushort* __restrict__ S, float* __restrict__ asum)
{
  const int hh = blockIdx.x, c = blockIdx.y, b = blockIdx.z;
  __shared__ float Bsm[CHUNKL][DSTATE];   // 64 KB
  __shared__ float Xsm[CHUNKL][HEADDIM];  // 32 KB
  __shared__ float dts[CHUNKL], acs[CHUNKL];
  const int tid = threadIdx.x;
  const int rbase = b*LSEQ + c*CHUNKL;
  if (tid < CHUNKL) dts[tid] = dt[(size_t)(rbase + tid)*NHEADS + hh];
  __syncthreads();
  if (tid == 0) {
    float Aval = -expf(A_log[hh]);
    float s = 0.f;
    for (int l = 0; l < CHUNKL; l++) { s += dts[l]*Aval; acs[l] = s; }
    asum[(b*NCHUNK + c)*NHEADS + hh] = s;
  }
  __syncthreads();
  const float alast = acs[CHUNKL-1];
  for (int i = tid; i < CHUNKL*DSTATE; i += 256) {
    int l = i >> 7, n = i & 127;
    Bsm[l][n] = b2f(bcb[(size_t)(rbase + l)*256 + n]);
  }
  for (int i = tid; i < CHUNKL*HEADDIM; i += 256) {
    int l = i >> 6, p = i & 63;
    Xsm[l][p] = b2f(xs[(size_t)(rbase + l)*DINNER + hh*HEADDIM + p]) * dts[l] * expf(alast - acs[l]);
  }
  __syncthreads();
  const int n0 = (tid & 31) * 4, p0 = (tid >> 5) * 8;
  float acc[8][4];
  #pragma unroll
  for (int i = 0; i < 8; i++) { acc[i][0]=0.f; acc[i][1]=0.f; acc[i][2]=0.f; acc[i][3]=0.f; }
  for (int l = 0; l < CHUNKL; l++) {
    float4 bv = *(const float4*)&Bsm[l][n0];
    float xv[8];
    *(float4*)&xv[0] = *(const float4*)&Xsm[l][p0];
    *(float4*)&xv[4] = *(const float4*)&Xsm[l][p0+4];
    #pragma unroll
    for (int i = 0; i < 8; i++) {
      acc[i][0] = fmaf(xv[i], bv.x, acc[i][0]);
      acc[i][1] = fmaf(xv[i], bv.y, acc[i][1]);
      acc[i][2] = fmaf(xv[i], bv.z, acc[i][2]);
      acc[i][3] = fmaf(xv[i], bv.w, acc[i][3]);
    }
  }
  ushort* Sp = S + (size_t)((b*NCHUNK + c)*NHEADS + hh) * (HEADDIM*DSTATE);
  #pragma unroll
  for (int i = 0; i < 8; i++) {
    ushort4 sv;
    sv.x = f2b(acc[i][0]); sv.y = f2b(acc[i][1]);
    sv.z = f2b(acc[i][2]); sv.w = f2b(acc[i][3]);
    *(ushort4*)&Sp[(p0+i)*DSTATE + n0] = sv;
  }
}

// ---------------- inter-chunk scan (in place: S becomes prev_states P), fp32 carry ----------------
__global__ __launch_bounds__(256) void scan_kernel(ushort* __restrict__ S, const float* __restrict__ asum)
{
  const int hh = blockIdx.x, b = blockIdx.y;
  const int tid = threadIdx.x;
  float carry[32];
  #pragma unroll
  for (int i = 0; i < 32; i++) carry[i] = 0.f;
  for (int c = 0; c < NCHUNK; c++) {
    ushort* Sp = S + (size_t)((b*NCHUNK + c)*NHEADS + hh) * 8192;
    float dec = expf(asum[(b*NCHUNK + c)*NHEADS + hh]);
    #pragma unroll
    for (int i = 0; i < 32; i++) {
      float sv = b2f(Sp[tid + i*256]);
      Sp[tid + i*256] = f2b(carry[i]);
      carry[i] = fmaf(dec, carry[i], sv);
    }
  }
}

// ---------------- yssd MFMA: Y = exp(acs)*C.P^T + M.X + D*xs ----------------
// per block (h, c, b): 3 bf16 GEMMs via mfma_f32_16x16x32_bf16
__global__ __launch_bounds__(256) void yssd_mfma(
    const ushort* __restrict__ xs, const ushort* __restrict__ bcb, const float* __restrict__ dt,
    const float* __restrict__ A_log, const float* __restrict__ Dvec,
    const ushort* __restrict__ S, ushort* __restrict__ y)
{
  constexpr int LDP = 136;               // +8 pad: row bank-shift 4 -> 2-way max (free)
  __shared__ ushort lC [128*LDP];        // C[l][n]
  __shared__ ushort lBM[128*LDP];        // B[s][n], then M[l][s]
  __shared__ ushort lP [64*LDP];         // P[p][n]
  __shared__ ushort lXT[64*LDP];         // X^T[p][s]
  __shared__ float dts[CHUNKL], acs[CHUNKL];
  __shared__ float wtot;
  const int hh = blockIdx.x, c = blockIdx.y, b = blockIdx.z;
  const int tid = threadIdx.x;
  const int lane = tid & 63;
  const int w = tid >> 6;
  const int rbase = b*LSEQ + c*CHUNKL;
  const size_t sbase = (size_t)((b*NCHUNK + c)*NHEADS + hh) * 8192;

  // stage B, C (row-major [row][128] -> padded LDS)
  #pragma unroll
  for (int it = 0; it < 8; it++) {
    int chunk = tid + it*256;            // 2048 chunks of 8 elems
    int l = chunk >> 4, c8 = chunk & 15;
    const ushort* src = bcb + (size_t)(rbase + l)*256 + c8*8;
    *(uint4*)&lBM[l*LDP + c8*8] = *(const uint4*)src;
    *(uint4*)&lC [l*LDP + c8*8] = *(const uint4*)(src + 128);
  }
  // stage P[p][n]
  #pragma unroll
  for (int it = 0; it < 4; it++) {
    int chunk = tid + it*256;            // 1024 chunks
    int p = chunk >> 4, c8 = chunk & 15;
    *(uint4*)&lP[p*LDP + c8*8] = *(const uint4*)(S + sbase + p*128 + c8*8);
  }
  // stage X^T[p][s] (transposing scatter)
  #pragma unroll
  for (int it = 0; it < 4; it++) {
    int chunk = tid + it*256;            // 1024 chunks of 8 p
    int s = chunk >> 3, p0 = (chunk & 7)*8;
    ushort tmp[8];
    *(uint4*)tmp = *(const uint4*)(xs + (size_t)(rbase + s)*DINNER + hh*HEADDIM + p0);
    #pragma unroll
    for (int u = 0; u < 8; u++) lXT[(p0+u)*LDP + s] = tmp[u];
  }
  // dt load + wave-parallel inclusive scan (2 waves of 64)
  float pre = 0.f;
  if (tid < 128) {
    float myv = dt[(size_t)(rbase + tid)*NHEADS + hh];
    dts[tid] = myv;
    pre = myv;
    #pragma unroll
    for (int o = 1; o < 64; o <<= 1) {
      float u = __shfl_up(pre, o, 64);
      if ((tid & 63) >= o) pre += u;
    }
    if (tid == 63) wtot = pre;
  }
  __syncthreads();
  if (tid < 128) {
    float Aval = -expf(A_log[hh]);
    acs[tid] = (pre + ((tid >= 64) ? wtot : 0.f)) * Aval;
  }

  const int rl = lane & 15;              // fragment row select
  const int kq = (lane >> 4) * 8;        // fragment k offset
  const int colL = lane & 15;            // C/D col
  const int rowQ = (lane >> 4) * 4;      // C/D row base

  // ---- GEMM1: G[l][s] = sum_n C[l][n]*B[s][n], 128x128, wave tile 64x64
  const int wm = (w & 1) * 64;
  const int wn = (w >> 1) * 64;
  f32x4 G[4][4];
  #pragma unroll
  for (int i = 0; i < 4; i++)
    #pragma unroll
    for (int j = 0; j < 4; j++) G[i][j] = (f32x4)(0.f);
  #pragma unroll
  for (int k0 = 0; k0 < 128; k0 += 32) {
    bf16x8 af[4], bfr[4];
    #pragma unroll
    for (int i = 0; i < 4; i++) af[i]  = *(const bf16x8*)&lC [(wm + i*16 + rl)*LDP + k0 + kq];
    #pragma unroll
    for (int j = 0; j < 4; j++) bfr[j] = *(const bf16x8*)&lBM[(wn + j*16 + rl)*LDP + k0 + kq];
    #pragma unroll
    for (int i = 0; i < 4; i++)
      #pragma unroll
      for (int j = 0; j < 4; j++)
        G[i][j] = __builtin_amdgcn_mfma_f32_16x16x32_bf16(af[i], bfr[j], G[i][j], 0, 0, 0);
  }
  __syncthreads();   // all waves done reading lBM(B); acs visible

  // ---- M[l][s] = (l>=s) ? G*exp(acs[l]-acs[s])*dt[s] : 0  -> overwrite lBM
  #pragma unroll
  for (int j = 0; j < 4; j++) {
    int sIdx = wn + j*16 + colL;
    float as = acs[sIdx];
    float ds = dts[sIdx];
    #pragma unroll
    for (int i = 0; i < 4; i++) {
      #pragma unroll
      for (int r = 0; r < 4; r++) {
        int lIdx = wm + i*16 + rowQ + r;
        float m = (lIdx >= sIdx) ? G[i][j][r] * expf(acs[lIdx] - as) * ds : 0.f;
        lBM[lIdx*LDP + sIdx] = f2b(m);
      }
    }
  }

  // ---- GEMM-off: Y[l][p] = sum_n C[l][n]*P[p][n], 128x64, wave tile 32x64
  const int om = w * 32;
  f32x4 Y[2][4];
  #pragma unroll
  for (int i = 0; i < 2; i++)
    #pragma unroll
    for (int j = 0; j < 4; j++) Y[i][j] = (f32x4)(0.f);
  #pragma unroll
  for (int k0 = 0; k0 < 128; k0 += 32) {
    bf16x8 a2[2], b2[4];
    #pragma unroll
    for (int i = 0; i < 2; i++) a2[i] = *(const bf16x8*)&lC[(om + i*16 + rl)*LDP + k0 + kq];
    #pragma unroll
    for (int j = 0; j < 4; j++) b2[j] = *(const bf16x8*)&lP[(j*16 + rl)*LDP + k0 + kq];
    #pragma unroll
    for (int i = 0; i < 2; i++)
      #pragma unroll
      for (int j = 0; j < 4; j++)
        Y[i][j] = __builtin_amdgcn_mfma_f32_16x16x32_bf16(a2[i], b2[j], Y[i][j], 0, 0, 0);
  }
  // row-scale by exp(acs[l])  (C/D layout: reg r = row)
  #pragma unroll
  for (int i = 0; i < 2; i++)
    #pragma unroll
    for (int r = 0; r < 4; r++) {
      float e = expf(acs[om + i*16 + rowQ + r]);
      #pragma unroll
      for (int j = 0; j < 4; j++) Y[i][j][r] *= e;
    }
  __syncthreads();   // M writes visible

  // ---- GEMM-diag: Y[l][p] += sum_s M[l][s]*XT[p][s]
  #pragma unroll
  for (int k0 = 0; k0 < 128; k0 += 32) {
    bf16x8 a3[2], b3[4];
    #pragma unroll
    for (int i = 0; i < 2; i++) a3[i] = *(const bf16x8*)&lBM[(om + i*16 + rl)*LDP + k0 + kq];
    #pragma unroll
    for (int j = 0; j < 4; j++) b3[j] = *(const bf16x8*)&lXT[(j*16 + rl)*LDP + k0 + kq];
    #pragma unroll
    for (int i = 0; i < 2; i++)
      #pragma unroll
      for (int j = 0; j < 4; j++)
        Y[i][j] = __builtin_amdgcn_mfma_f32_16x16x32_bf16(a3[i], b3[j], Y[i][j], 0, 0, 0);
  }

  // ---- epilogue: += D*xs, write bf16
  const float Dh = Dvec[hh];
  #pragma unroll
  for (int i = 0; i < 2; i++) {
    #pragma unroll
    for (int r = 0; r < 4; r++) {
      int lIdx = om + i*16 + rowQ + r;
      ushort* yrow = y + (size_t)(rbase + lIdx)*DINNER + hh*HEADDIM;
      #pragma unroll
      for (int j = 0; j < 4; j++) {
        int p = j*16 + colL;
        float val = Y[i][j][r] + Dh * b2f(lXT[p*LDP + lIdx]);
        yrow[p] = f2b(val);
      }
    }
  }
}

// ---------------- gated RMSNorm (in place on y, bf16) ----------------
__global__ __launch_bounds__(256) void rmsnorm_kernel(ushort* __restrict__ y,
    const ushort* __restrict__ z, const float* __restrict__ nw)
{
  const int row = blockIdx.x;
  const int t = threadIdx.x;
  ushort* yr = y + (size_t)row*DINNER;
  const ushort* zr = z + (size_t)row*DINNER;
  float v[8];
  float ss = 0.f;
  #pragma unroll
  for (int i = 0; i < 8; i++) {
    int c = t + i*256;
    float zz = b2f(zr[c]);
    float g = b2f(yr[c]) * (zz / (1.f + expf(-zz)));
    v[i] = g;
    ss += g*g;
  }
  #pragma unroll
  for (int o = 32; o > 0; o >>= 1) ss += __shfl_down(ss, o, 64);
  __shared__ float red[4];
  if ((t & 63) == 0) red[t >> 6] = ss;
  __syncthreads();
  float scale = rsqrtf((red[0]+red[1]+red[2]+red[3]) * (1.f/DINNER) + 1e-5f);
  #pragma unroll
  for (int i = 0; i < 8; i++) {
    int c = t + i*256;
    yr[c] = f2b(v[i]*scale*nw[c]);
  }
}

extern "C" void kernel_launch(void* const* d_in, const int* in_sizes, int n_in,
                              void* d_out, int out_size, void* d_ws, size_t ws_size,
                              hipStream_t stream)
{
  const float* x    = (const float*)d_in[0];
  const float* lnw  = (const float*)d_in[1];
  const float* lnb  = (const float*)d_in[2];
  const float* win  = (const float*)d_in[3];
  const float* cw   = (const float*)d_in[4];
  const float* cb   = (const float*)d_in[5];
  const float* dtb  = (const float*)d_in[6];
  const float* alog = (const float*)d_in[7];
  const float* dvec = (const float*)d_in[8];
  const float* nw   = (const float*)d_in[9];
  const float* wout = (const float*)d_in[10];
  float* out = (float*)d_out;
  char* ws = (char*)d_ws;
  (void)in_sizes; (void)n_in; (void)out_size;

  if (ws_size < B_END) return;  // workspace too small: fail cleanly, don't fault

  ushort* zb   = (ushort*)(ws + B_Z);
  ushort* xbcb = (ushort*)(ws + B_XBC);
  float*  dtr  = (float*) (ws + B_DT);
  ushort* xsb  = (ushort*)(ws + B_XS);
  ushort* bcb  = (ushort*)(ws + B_BC);
  ushort* yb   = (ushort*)(ws + B_Y);
  float*  asum = (float*) (ws + B_ASUM);
  ushort* Sb   = xbcb;                                        // aliases xbc (dead after conv)
  ushort* hb   = yb;                                          // aliases y[0 : 16.8MB]
  ushort* winB = (ushort*)(ws + B_Y + (size_t)ROWS*DMODEL*2); // aliases y[16.8MB : 26MB]
  ushort* woutB= (ushort*)(ws + B_XBC + (size_t)BATCH*NCHUNK*NHEADS*HEADDIM*DSTATE*2); // XBC tail (4.19MB)

  hipLaunchKernelGGL(convert_win_kernel, dim3((NPAD*DMODEL)/256), dim3(256), 0, stream, win, winB);
  hipLaunchKernelGGL(ln_kernel, dim3(ROWS), dim3(256), 0, stream, x, lnw, lnb, hb);
  hipLaunchKernelGGL(gemm_inproj_mfma, dim3(64, 35), dim3(256), 0, stream, hb, winB, zb, xbcb, dtr);
  hipLaunchKernelGGL(dt_kernel, dim3(ROWS*NHEADS/256), dim3(256), 0, stream, dtr, dtb);
  hipLaunchKernelGGL(conv_kernel, dim3(9, ROWS), dim3(256), 0, stream, xbcb, cw, cb, xsb, bcb);
  hipLaunchKernelGGL(convert_wout_kernel, dim3((DMODEL*DINNER)/256), dim3(256), 0, stream, wout, woutB);
  hipLaunchKernelGGL(states_kernel, dim3(NHEADS, NCHUNK, BATCH), dim3(256), 0, stream,
                     xsb, bcb, dtr, alog, Sb, asum);
  hipLaunchKernelGGL(scan_kernel, dim3(NHEADS, BATCH), dim3(256), 0, stream, Sb, asum);
  hipLaunchKernelGGL(yssd_mfma, dim3(NHEADS, NCHUNK, BATCH), dim3(256), 0, stream,
                     xsb, bcb, dtr, alog, dvec, Sb, yb);
  hipLaunchKernelGGL(rmsnorm_kernel, dim3(ROWS), dim3(256), 0, stream, yb, zb, nw);
  hipLaunchKernelGGL(gemm_outproj_mfma, dim3(64, 8), dim3(256), 0, stream, yb, woutB, x, out);
}

// Round 5
// 504.180 us; speedup vs baseline: 3.8258x; 1.3104x over previous
//
#include <hip/hip_runtime.h>
#include <math.h>

#define BATCH   4
#define LSEQ    2048
#define DMODEL  1024
#define DSTATE  128
#define HEADDIM 64
#define DINNER  2048
#define NHEADS  32
#define CONVCH  2304
#define DINPROJ 4384
#define NPAD    4480
#define CHUNKL  128
#define NCHUNK  16
#define ROWS    (BATCH*LSEQ)

// ---------------- workspace layout (BYTE offsets) ----------------
#define B_Z     ((size_t)0)                              // ROWS*DINNER bf16
#define B_XBC   (B_Z   + (size_t)ROWS*DINNER*2)          // ROWS*CONVCH bf16; S aliases first 33.55MB; Wout bf16 aliases tail 4.19MB
#define B_DT    (B_XBC + (size_t)ROWS*CONVCH*2)          // ROWS*NHEADS fp32
#define B_XS    (B_DT  + (size_t)ROWS*NHEADS*4)          // ROWS*DINNER bf16
#define B_BC    (B_XS  + (size_t)ROWS*DINNER*2)          // ROWS*256 bf16
#define B_Y     (B_BC  + (size_t)ROWS*256*2)             // ROWS*DINNER bf16; h bf16 aliases [0,16.8MB); Win bf16 aliases [16.8MB,26MB)
#define B_ASUM  (B_Y   + (size_t)ROWS*DINNER*2)          // BATCH*NCHUNK*NHEADS fp32
#define B_END   (B_ASUM + (size_t)BATCH*NCHUNK*NHEADS*4) // ~137 MB total

typedef __attribute__((ext_vector_type(8))) short bf16x8;
typedef __attribute__((ext_vector_type(4))) float f32x4;

__device__ __forceinline__ float b2f(ushort u) {
  union { uint32_t i; float f; } v; v.i = ((uint32_t)u) << 16; return v.f;
}
__device__ __forceinline__ ushort f2b(float f) {
  union { float f; uint32_t i; } v; v.f = f;
  uint32_t r = (v.i + 0x7FFFu + ((v.i >> 16) & 1u)) >> 16;
  return (ushort)r;
}

__device__ __forceinline__ void async_ld16(const void* g, void* l) {
  __builtin_amdgcn_global_load_lds(
      (const __attribute__((address_space(1))) unsigned int*)g,
      (__attribute__((address_space(3))) unsigned int*)l, 16, 0, 0);
}

// ---------------- weight fp32 -> bf16 converters ----------------
__global__ __launch_bounds__(256) void convert_win_kernel(const float* __restrict__ W,
                                                          ushort* __restrict__ Wb)
{
  size_t i = (size_t)blockIdx.x*256 + threadIdx.x;  // grid covers NPAD*DMODEL
  Wb[i] = (i < (size_t)DINPROJ*DMODEL) ? f2b(W[i]) : (ushort)0;
}

__global__ __launch_bounds__(256) void convert_wout_kernel(const float* __restrict__ W,
                                                           ushort* __restrict__ Wb)
{
  size_t i = (size_t)blockIdx.x*256 + threadIdx.x;  // DMODEL*DINNER
  Wb[i] = f2b(W[i]);
}

// ---------------- LayerNorm -> h (bf16) ----------------
__global__ __launch_bounds__(256) void ln_kernel(const float* __restrict__ x,
    const float* __restrict__ w, const float* __restrict__ bias, ushort* __restrict__ h)
{
  const int row = blockIdx.x;
  const int t = threadIdx.x;
  const float* xr = x + (size_t)row * DMODEL;
  float v[4];
  float s = 0.f;
  #pragma unroll
  for (int i = 0; i < 4; i++) { v[i] = xr[t + i*256]; s += v[i]; }
  __shared__ float red[4];
  #pragma unroll
  for (int o = 32; o > 0; o >>= 1) s += __shfl_down(s, o, 64);
  if ((t & 63) == 0) red[t >> 6] = s;
  __syncthreads();
  float mean = (red[0]+red[1]+red[2]+red[3]) * (1.f/DMODEL);
  float vs = 0.f;
  #pragma unroll
  for (int i = 0; i < 4; i++) { float d = v[i]-mean; vs += d*d; }
  #pragma unroll
  for (int o = 32; o > 0; o >>= 1) vs += __shfl_down(vs, o, 64);
  __syncthreads();
  if ((t & 63) == 0) red[t >> 6] = vs;
  __syncthreads();
  float rstd = rsqrtf((red[0]+red[1]+red[2]+red[3]) * (1.f/DMODEL) + 1e-5f);
  ushort* hr = h + (size_t)row * DMODEL;
  #pragma unroll
  for (int i = 0; i < 4; i++) {
    int c = t + i*256;
    hr[c] = f2b((v[i]-mean)*rstd*w[c] + bias[c]);
  }
}

// ---------------- in_proj MFMA GEMM: [8192][4480] = h[8192][1024] @ Wpad[4480][1024]^T ----------------
// epilogue: block-uniform routing (tile boundaries align with z/xbc/dt splits) + LDS-restaged uint4 stores
__global__ __launch_bounds__(256) void gemm_inproj_mfma(const ushort* __restrict__ A,
    const ushort* __restrict__ W, ushort* __restrict__ z, ushort* __restrict__ xbc,
    float* __restrict__ dtr)
{
  constexpr int K = DMODEL;
  __shared__ ushort smem[128*136];     // staging aliases first 16KB; epilogue restage uses all (padded 136)
  ushort* lA = smem;
  ushort* lB = smem + 4096;
  const int tid = threadIdx.x;
  const int lane = tid & 63;
  const int w = tid >> 6;
  const int m0 = blockIdx.x * 128;
  const int n0 = blockIdx.y * 128;
  const int wm = (w & 1) * 64;
  const int wn = (w >> 1) * 64;
  f32x4 acc[4][4];
  #pragma unroll
  for (int i = 0; i < 4; i++)
    #pragma unroll
    for (int j = 0; j < 4; j++) acc[i][j] = (f32x4)(0.f);

  for (int k0 = 0; k0 < K; k0 += 32) {
    __syncthreads();
    #pragma unroll
    for (int is = 0; is < 2; is++) {
      int c = w*128 + is*64 + lane;
      int row = c >> 2, cb = c & 3;
      async_ld16(A + (size_t)(m0 + row)*K + k0 + cb*8, lA + (size_t)(w*128 + is*64)*8);
      async_ld16(W + (size_t)(n0 + row)*K + k0 + cb*8, lB + (size_t)(w*128 + is*64)*8);
    }
    __syncthreads();
    bf16x8 af[4], bfr[4];
    #pragma unroll
    for (int i = 0; i < 4; i++)
      af[i] = *(const bf16x8*)&lA[(wm + i*16 + (lane & 15))*32 + (lane >> 4)*8];
    #pragma unroll
    for (int j = 0; j < 4; j++)
      bfr[j] = *(const bf16x8*)&lB[(wn + j*16 + (lane & 15))*32 + (lane >> 4)*8];
    #pragma unroll
    for (int i = 0; i < 4; i++)
      #pragma unroll
      for (int j = 0; j < 4; j++)
        acc[i][j] = __builtin_amdgcn_mfma_f32_16x16x32_bf16(af[i], bfr[j], acc[i][j], 0, 0, 0);
  }

  const int col_l = lane & 15;
  const int row_l = (lane >> 4) * 4;
  __syncthreads();   // all frag reads done before smem reuse
  if (n0 < DINNER + CONVCH) {
    #pragma unroll
    for (int i = 0; i < 4; i++)
      #pragma unroll
      for (int j = 0; j < 4; j++)
        #pragma unroll
        for (int r = 0; r < 4; r++)
          smem[(wm + i*16 + row_l + r)*136 + wn + j*16 + col_l] = f2b(acc[i][j][r]);
    __syncthreads();
    ushort* outp; int coff, ncols;
    if (n0 < DINNER) { outp = z;   coff = n0;          ncols = DINNER; }
    else             { outp = xbc; coff = n0 - DINNER; ncols = CONVCH; }
    #pragma unroll
    for (int it = 0; it < 8; it++) {
      int idx = tid + it*256;
      int row = idx >> 4, c8 = idx & 15;
      *(uint4*)(outp + (size_t)(m0 + row)*ncols + coff + c8*8) = *(const uint4*)&smem[row*136 + c8*8];
    }
  } else {
    // dt tile: only local cols [0,32) are real (4352..4383)
    #pragma unroll
    for (int i = 0; i < 4; i++)
      #pragma unroll
      for (int j = 0; j < 2; j++) {
        int lc = wn + j*16 + col_l;
        if (lc < 32) {
          #pragma unroll
          for (int r = 0; r < 4; r++)
            dtr[(size_t)(m0 + wm + i*16 + row_l + r)*NHEADS + lc] = acc[i][j][r];
        }
      }
  }
}

// ---------------- out_proj MFMA GEMM + residual ----------------
__global__ __launch_bounds__(256) void gemm_outproj_mfma(const ushort* __restrict__ A,
    const ushort* __restrict__ W, const float* __restrict__ x, float* __restrict__ out)
{
  constexpr int K = DINNER;
  __shared__ ushort lA[128*32];
  __shared__ ushort lB[128*32];
  const int tid = threadIdx.x;
  const int lane = tid & 63;
  const int w = tid >> 6;
  const int m0 = blockIdx.x * 128;
  const int n0 = blockIdx.y * 128;
  const int wm = (w & 1) * 64;
  const int wn = (w >> 1) * 64;
  f32x4 acc[4][4];
  #pragma unroll
  for (int i = 0; i < 4; i++)
    #pragma unroll
    for (int j = 0; j < 4; j++) acc[i][j] = (f32x4)(0.f);

  for (int k0 = 0; k0 < K; k0 += 32) {
    __syncthreads();
    #pragma unroll
    for (int is = 0; is < 2; is++) {
      int c = w*128 + is*64 + lane;
      int row = c >> 2, cb = c & 3;
      async_ld16(A + (size_t)(m0 + row)*K + k0 + cb*8, lA + (size_t)(w*128 + is*64)*8);
      async_ld16(W + (size_t)(n0 + row)*K + k0 + cb*8, lB + (size_t)(w*128 + is*64)*8);
    }
    __syncthreads();
    bf16x8 af[4], bfr[4];
    #pragma unroll
    for (int i = 0; i < 4; i++)
      af[i] = *(const bf16x8*)&lA[(wm + i*16 + (lane & 15))*32 + (lane >> 4)*8];
    #pragma unroll
    for (int j = 0; j < 4; j++)
      bfr[j] = *(const bf16x8*)&lB[(wn + j*16 + (lane & 15))*32 + (lane >> 4)*8];
    #pragma unroll
    for (int i = 0; i < 4; i++)
      #pragma unroll
      for (int j = 0; j < 4; j++)
        acc[i][j] = __builtin_amdgcn_mfma_f32_16x16x32_bf16(af[i], bfr[j], acc[i][j], 0, 0, 0);
  }

  const int col_l = lane & 15;
  const int row_l = (lane >> 4) * 4;
  #pragma unroll
  for (int i = 0; i < 4; i++) {
    #pragma unroll
    for (int j = 0; j < 4; j++) {
      int gn = n0 + wn + j*16 + col_l;
      #pragma unroll
      for (int r = 0; r < 4; r++) {
        int gm = m0 + wm + i*16 + row_l + r;
        out[(size_t)gm*DMODEL + gn] = acc[i][j][r] + x[(size_t)gm*DMODEL + gn];
      }
    }
  }
}

// ---------------- dt = softplus(dt_raw + bias), in place (fp32) ----------------
__global__ __launch_bounds__(256) void dt_kernel(float* __restrict__ dtr, const float* __restrict__ dtb)
{
  int i = blockIdx.x*256 + threadIdx.x;
  float v = dtr[i] + dtb[i & (NHEADS-1)];
  dtr[i] = (v > 20.f) ? v : log1pf(expf(v));
}

// ---------------- causal conv4 + SiLU, LDS row-tiled: read each input once ----------------
__global__ __launch_bounds__(256) void conv_tiled(const ushort* __restrict__ xbc,
    const float* __restrict__ cw, const float* __restrict__ cb,
    ushort* __restrict__ xs, ushort* __restrict__ bcb)
{
  __shared__ ushort tile[35*256];            // rows [l0-3, l0+32) x 256 ch
  const int tid = threadIdx.x;
  const int ch0 = blockIdx.x * 256;
  const int row0 = blockIdx.y * 32;          // never spans a batch boundary (32 | 2048)
  const int l0 = row0 & (LSEQ-1);
  for (int idx = tid; idx < 35*32; idx += 256) {
    int r = idx >> 5, c16 = idx & 31;
    uint4 v = make_uint4(0,0,0,0);
    if (l0 + r - 3 >= 0)
      v = *(const uint4*)(xbc + (size_t)(row0 + r - 3)*CONVCH + ch0 + c16*8);
    *(uint4*)&tile[r*256 + c16*8] = v;
  }
  __syncthreads();
  const int ch = ch0 + tid;
  const float w0 = cw[ch*4+0], w1 = cw[ch*4+1], w2 = cw[ch*4+2], w3 = cw[ch*4+3];
  const float bias = cb[ch];
  const bool isX = (ch0 < DINNER);
  #pragma unroll 4
  for (int r = 0; r < 32; r++) {
    float acc = bias;
    acc = fmaf(b2f(tile[(r+0)*256 + tid]), w0, acc);
    acc = fmaf(b2f(tile[(r+1)*256 + tid]), w1, acc);
    acc = fmaf(b2f(tile[(r+2)*256 + tid]), w2, acc);
    acc = fmaf(b2f(tile[(r+3)*256 + tid]), w3, acc);
    float v = acc / (1.f + expf(-acc));
    if (isX) xs[(size_t)(row0 + r)*DINNER + ch] = f2b(v);
    else     bcb[(size_t)(row0 + r)*256 + (ch - DINNER)] = f2b(v);
  }
}

// ---------------- per-chunk states via MFMA: S[p][n] = sum_l Xw[l][p]*B[l][n] ----------------
__global__ __launch_bounds__(256) void states_mfma(
    const ushort* __restrict__ xs, const ushort* __restrict__ bcb, const float* __restrict__ dt,
    const float* __restrict__ A_log, ushort* __restrict__ S, float* __restrict__ asum)
{
  constexpr int LDP = 136;
  __shared__ ushort lBT[128*LDP];   // B^T[n][l]
  __shared__ ushort lXT[64*LDP];    // Xw^T[p][l]; reused for S restage
  __shared__ float dts[CHUNKL], acs[CHUNKL];
  __shared__ float wtot;
  const int hh = blockIdx.x, c = blockIdx.y, b = blockIdx.z;
  const int tid = threadIdx.x;
  const int lane = tid & 63;
  const int w = tid >> 6;
  const int rbase = b*LSEQ + c*CHUNKL;
  const size_t sbase = (size_t)((b*NCHUNK + c)*NHEADS + hh) * 8192;

  // dt load + wave-parallel inclusive scan (2 waves of 64)
  float pre = 0.f;
  if (tid < 128) {
    float myv = dt[(size_t)(rbase + tid)*NHEADS + hh];
    dts[tid] = myv;
    pre = myv;
    #pragma unroll
    for (int o = 1; o < 64; o <<= 1) {
      float u = __shfl_up(pre, o, 64);
      if ((tid & 63) >= o) pre += u;
    }
    if (tid == 63) wtot = pre;
  }
  // stage B^T (independent of scan)
  #pragma unroll
  for (int it = 0; it < 8; it++) {
    int chunk = tid + it*256;
    int l = chunk >> 4, n8 = chunk & 15;
    ushort tmp[8];
    *(uint4*)tmp = *(const uint4*)(bcb + (size_t)(rbase + l)*256 + n8*8);
    #pragma unroll
    for (int u = 0; u < 8; u++) lBT[(n8*8+u)*LDP + l] = tmp[u];
  }
  __syncthreads();
  float alast_loc = 0.f;
  if (tid < 128) {
    float Aval = -expf(A_log[hh]);
    float a = (pre + ((tid >= 64) ? wtot : 0.f)) * Aval;
    acs[tid] = a;
    if (tid == 127) { asum[(b*NCHUNK + c)*NHEADS + hh] = a; }
  }
  __syncthreads();
  alast_loc = acs[CHUNKL-1];
  // stage Xw^T[p][l] = xs[l][p]*dt[l]*exp(alast-acs[l])
  #pragma unroll
  for (int it = 0; it < 4; it++) {
    int chunk = tid + it*256;
    int l = chunk >> 3, p8 = (chunk & 7)*8;
    ushort tmp[8];
    *(uint4*)tmp = *(const uint4*)(xs + (size_t)(rbase + l)*DINNER + hh*HEADDIM + p8);
    float wl = dts[l] * expf(alast_loc - acs[l]);
    #pragma unroll
    for (int u = 0; u < 8; u++) lXT[(p8+u)*LDP + l] = f2b(b2f(tmp[u]) * wl);
  }
  __syncthreads();

  // GEMM: D[m=p(64)][n(128)], wave w covers n in [w*32, w*32+32)
  const int rl = lane & 15;
  const int kq = (lane >> 4) * 8;
  const int nb = w * 32;
  f32x4 acc[4][2];
  #pragma unroll
  for (int i = 0; i < 4; i++) { acc[i][0] = (f32x4)(0.f); acc[i][1] = (f32x4)(0.f); }
  #pragma unroll
  for (int k0 = 0; k0 < 128; k0 += 32) {
    bf16x8 af[4], bfr[2];
    #pragma unroll
    for (int i = 0; i < 4; i++) af[i]  = *(const bf16x8*)&lXT[(i*16 + rl)*LDP + k0 + kq];
    #pragma unroll
    for (int j = 0; j < 2; j++) bfr[j] = *(const bf16x8*)&lBT[(nb + j*16 + rl)*LDP + k0 + kq];
    #pragma unroll
    for (int i = 0; i < 4; i++)
      #pragma unroll
      for (int j = 0; j < 2; j++)
        acc[i][j] = __builtin_amdgcn_mfma_f32_16x16x32_bf16(af[i], bfr[j], acc[i][j], 0, 0, 0);
  }
  __syncthreads();   // frag reads done; reuse lXT for S restage
  const int colL = lane & 15;
  const int rowQ = (lane >> 4) * 4;
  #pragma unroll
  for (int i = 0; i < 4; i++)
    #pragma unroll
    for (int j = 0; j < 2; j++)
      #pragma unroll
      for (int r = 0; r < 4; r++)
        lXT[(i*16 + rowQ + r)*LDP + nb + j*16 + colL] = f2b(acc[i][j][r]);
  __syncthreads();
  #pragma unroll
  for (int it = 0; it < 4; it++) {
    int idx = tid + it*256;
    int row = idx >> 4, c8 = idx & 15;
    *(uint4*)(S + sbase + row*128 + c8*8) = *(const uint4*)&lXT[row*LDP + c8*8];
  }
}

// ---------------- inter-chunk scan (in place: S becomes prev_states P), fp32 carry ----------------
__global__ __launch_bounds__(256) void scan_kernel(ushort* __restrict__ S, const float* __restrict__ asum)
{
  const int hh = blockIdx.x, b = blockIdx.y;
  const int tid = threadIdx.x;
  float carry[32];
  #pragma unroll
  for (int i = 0; i < 32; i++) carry[i] = 0.f;
  for (int c = 0; c < NCHUNK; c++) {
    ushort* Sp = S + (size_t)((b*NCHUNK + c)*NHEADS + hh) * 8192;
    float dec = expf(asum[(b*NCHUNK + c)*NHEADS + hh]);
    #pragma unroll
    for (int i = 0; i < 32; i++) {
      float sv = b2f(Sp[tid + i*256]);
      Sp[tid + i*256] = f2b(carry[i]);
      carry[i] = fmaf(dec, carry[i], sv);
    }
  }
}

// ---------------- yssd MFMA: Y = exp(acs)*C.P^T + M.X + D*xs ----------------
__global__ __launch_bounds__(256) void yssd_mfma(
    const ushort* __restrict__ xs, const ushort* __restrict__ bcb, const float* __restrict__ dt,
    const float* __restrict__ A_log, const float* __restrict__ Dvec,
    const ushort* __restrict__ S, ushort* __restrict__ y)
{
  constexpr int LDP = 136;
  __shared__ ushort lC [128*LDP];
  __shared__ ushort lBM[128*LDP];
  __shared__ ushort lP [64*LDP];
  __shared__ ushort lXT[64*LDP];
  __shared__ float dts[CHUNKL], acs[CHUNKL];
  __shared__ float wtot;
  const int hh = blockIdx.x, c = blockIdx.y, b = blockIdx.z;
  const int tid = threadIdx.x;
  const int lane = tid & 63;
  const int w = tid >> 6;
  const int rbase = b*LSEQ + c*CHUNKL;
  const size_t sbase = (size_t)((b*NCHUNK + c)*NHEADS + hh) * 8192;

  #pragma unroll
  for (int it = 0; it < 8; it++) {
    int chunk = tid + it*256;
    int l = chunk >> 4, c8 = chunk & 15;
    const ushort* src = bcb + (size_t)(rbase + l)*256 + c8*8;
    *(uint4*)&lBM[l*LDP + c8*8] = *(const uint4*)src;
    *(uint4*)&lC [l*LDP + c8*8] = *(const uint4*)(src + 128);
  }
  #pragma unroll
  for (int it = 0; it < 4; it++) {
    int chunk = tid + it*256;
    int p = chunk >> 4, c8 = chunk & 15;
    *(uint4*)&lP[p*LDP + c8*8] = *(const uint4*)(S + sbase + p*128 + c8*8);
  }
  #pragma unroll
  for (int it = 0; it < 4; it++) {
    int chunk = tid + it*256;
    int s = chunk >> 3, p0 = (chunk & 7)*8;
    ushort tmp[8];
    *(uint4*)tmp = *(const uint4*)(xs + (size_t)(rbase + s)*DINNER + hh*HEADDIM + p0);
    #pragma unroll
    for (int u = 0; u < 8; u++) lXT[(p0+u)*LDP + s] = tmp[u];
  }
  float pre = 0.f;
  if (tid < 128) {
    float myv = dt[(size_t)(rbase + tid)*NHEADS + hh];
    dts[tid] = myv;
    pre = myv;
    #pragma unroll
    for (int o = 1; o < 64; o <<= 1) {
      float u = __shfl_up(pre, o, 64);
      if ((tid & 63) >= o) pre += u;
    }
    if (tid == 63) wtot = pre;
  }
  __syncthreads();
  if (tid < 128) {
    float Aval = -expf(A_log[hh]);
    acs[tid] = (pre + ((tid >= 64) ? wtot : 0.f)) * Aval;
  }

  const int rl = lane & 15;
  const int kq = (lane >> 4) * 8;
  const int colL = lane & 15;
  const int rowQ = (lane >> 4) * 4;

  const int wm = (w & 1) * 64;
  const int wn = (w >> 1) * 64;
  f32x4 G[4][4];
  #pragma unroll
  for (int i = 0; i < 4; i++)
    #pragma unroll
    for (int j = 0; j < 4; j++) G[i][j] = (f32x4)(0.f);
  #pragma unroll
  for (int k0 = 0; k0 < 128; k0 += 32) {
    bf16x8 af[4], bfr[4];
    #pragma unroll
    for (int i = 0; i < 4; i++) af[i]  = *(const bf16x8*)&lC [(wm + i*16 + rl)*LDP + k0 + kq];
    #pragma unroll
    for (int j = 0; j < 4; j++) bfr[j] = *(const bf16x8*)&lBM[(wn + j*16 + rl)*LDP + k0 + kq];
    #pragma unroll
    for (int i = 0; i < 4; i++)
      #pragma unroll
      for (int j = 0; j < 4; j++)
        G[i][j] = __builtin_amdgcn_mfma_f32_16x16x32_bf16(af[i], bfr[j], G[i][j], 0, 0, 0);
  }
  __syncthreads();

  #pragma unroll
  for (int j = 0; j < 4; j++) {
    int sIdx = wn + j*16 + colL;
    float as = acs[sIdx];
    float ds = dts[sIdx];
    #pragma unroll
    for (int i = 0; i < 4; i++) {
      #pragma unroll
      for (int r = 0; r < 4; r++) {
        int lIdx = wm + i*16 + rowQ + r;
        float m = (lIdx >= sIdx) ? G[i][j][r] * expf(acs[lIdx] - as) * ds : 0.f;
        lBM[lIdx*LDP + sIdx] = f2b(m);
      }
    }
  }

  const int om = w * 32;
  f32x4 Y[2][4];
  #pragma unroll
  for (int i = 0; i < 2; i++)
    #pragma unroll
    for (int j = 0; j < 4; j++) Y[i][j] = (f32x4)(0.f);
  #pragma unroll
  for (int k0 = 0; k0 < 128; k0 += 32) {
    bf16x8 a2[2], b2[4];
    #pragma unroll
    for (int i = 0; i < 2; i++) a2[i] = *(const bf16x8*)&lC[(om + i*16 + rl)*LDP + k0 + kq];
    #pragma unroll
    for (int j = 0; j < 4; j++) b2[j] = *(const bf16x8*)&lP[(j*16 + rl)*LDP + k0 + kq];
    #pragma unroll
    for (int i = 0; i < 2; i++)
      #pragma unroll
      for (int j = 0; j < 4; j++)
        Y[i][j] = __builtin_amdgcn_mfma_f32_16x16x32_bf16(a2[i], b2[j], Y[i][j], 0, 0, 0);
  }
  #pragma unroll
  for (int i = 0; i < 2; i++)
    #pragma unroll
    for (int r = 0; r < 4; r++) {
      float e = expf(acs[om + i*16 + rowQ + r]);
      #pragma unroll
      for (int j = 0; j < 4; j++) Y[i][j][r] *= e;
    }
  __syncthreads();

  #pragma unroll
  for (int k0 = 0; k0 < 128; k0 += 32) {
    bf16x8 a3[2], b3[4];
    #pragma unroll
    for (int i = 0; i < 2; i++) a3[i] = *(const bf16x8*)&lBM[(om + i*16 + rl)*LDP + k0 + kq];
    #pragma unroll
    for (int j = 0; j < 4; j++) b3[j] = *(const bf16x8*)&lXT[(j*16 + rl)*LDP + k0 + kq];
    #pragma unroll
    for (int i = 0; i < 2; i++)
      #pragma unroll
      for (int j = 0; j < 4; j++)
        Y[i][j] = __builtin_amdgcn_mfma_f32_16x16x32_bf16(a3[i], b3[j], Y[i][j], 0, 0, 0);
  }

  const float Dh = Dvec[hh];
  #pragma unroll
  for (int i = 0; i < 2; i++) {
    #pragma unroll
    for (int r = 0; r < 4; r++) {
      int lIdx = om + i*16 + rowQ + r;
      ushort* yrow = y + (size_t)(rbase + lIdx)*DINNER + hh*HEADDIM;
      #pragma unroll
      for (int j = 0; j < 4; j++) {
        int p = j*16 + colL;
        float val = Y[i][j][r] + Dh * b2f(lXT[p*LDP + lIdx]);
        yrow[p] = f2b(val);
      }
    }
  }
}

// ---------------- gated RMSNorm (in place on y, bf16) ----------------
__global__ __launch_bounds__(256) void rmsnorm_kernel(ushort* __restrict__ y,
    const ushort* __restrict__ z, const float* __restrict__ nw)
{
  const int row = blockIdx.x;
  const int t = threadIdx.x;
  ushort* yr = y + (size_t)row*DINNER;
  const ushort* zr = z + (size_t)row*DINNER;
  float v[8];
  float ss = 0.f;
  #pragma unroll
  for (int i = 0; i < 8; i++) {
    int c = t + i*256;
    float zz = b2f(zr[c]);
    float g = b2f(yr[c]) * (zz / (1.f + expf(-zz)));
    v[i] = g;
    ss += g*g;
  }
  #pragma unroll
  for (int o = 32; o > 0; o >>= 1) ss += __shfl_down(ss, o, 64);
  __shared__ float red[4];
  if ((t & 63) == 0) red[t >> 6] = ss;
  __syncthreads();
  float scale = rsqrtf((red[0]+red[1]+red[2]+red[3]) * (1.f/DINNER) + 1e-5f);
  #pragma unroll
  for (int i = 0; i < 8; i++) {
    int c = t + i*256;
    yr[c] = f2b(v[i]*scale*nw[c]);
  }
}

extern "C" void kernel_launch(void* const* d_in, const int* in_sizes, int n_in,
                              void* d_out, int out_size, void* d_ws, size_t ws_size,
                              hipStream_t stream)
{
  const float* x    = (const float*)d_in[0];
  const float* lnw  = (const float*)d_in[1];
  const float* lnb  = (const float*)d_in[2];
  const float* win  = (const float*)d_in[3];
  const float* cw   = (const float*)d_in[4];
  const float* cb   = (const float*)d_in[5];
  const float* dtb  = (const float*)d_in[6];
  const float* alog = (const float*)d_in[7];
  const float* dvec = (const float*)d_in[8];
  const float* nw   = (const float*)d_in[9];
  const float* wout = (const float*)d_in[10];
  float* out = (float*)d_out;
  char* ws = (char*)d_ws;
  (void)in_sizes; (void)n_in; (void)out_size;

  if (ws_size < B_END) return;  // workspace too small: fail cleanly, don't fault

  ushort* zb   = (ushort*)(ws + B_Z);
  ushort* xbcb = (ushort*)(ws + B_XBC);
  float*  dtr  = (float*) (ws + B_DT);
  ushort* xsb  = (ushort*)(ws + B_XS);
  ushort* bcb  = (ushort*)(ws + B_BC);
  ushort* yb   = (ushort*)(ws + B_Y);
  float*  asum = (float*) (ws + B_ASUM);
  ushort* Sb   = xbcb;                                        // aliases xbc (dead after conv)
  ushort* hb   = yb;                                          // aliases y[0 : 16.8MB]
  ushort* winB = (ushort*)(ws + B_Y + (size_t)ROWS*DMODEL*2); // aliases y[16.8MB : 26MB]
  ushort* woutB= (ushort*)(ws + B_XBC + (size_t)BATCH*NCHUNK*NHEADS*HEADDIM*DSTATE*2); // XBC tail (4.19MB)

  hipLaunchKernelGGL(convert_win_kernel, dim3((NPAD*DMODEL)/256), dim3(256), 0, stream, win, winB);
  hipLaunchKernelGGL(ln_kernel, dim3(ROWS), dim3(256), 0, stream, x, lnw, lnb, hb);
  hipLaunchKernelGGL(gemm_inproj_mfma, dim3(64, 35), dim3(256), 0, stream, hb, winB, zb, xbcb, dtr);
  hipLaunchKernelGGL(dt_kernel, dim3(ROWS*NHEADS/256), dim3(256), 0, stream, dtr, dtb);
  hipLaunchKernelGGL(conv_tiled, dim3(9, ROWS/32), dim3(256), 0, stream, xbcb, cw, cb, xsb, bcb);
  hipLaunchKernelGGL(convert_wout_kernel, dim3((DMODEL*DINNER)/256), dim3(256), 0, stream, wout, woutB);
  hipLaunchKernelGGL(states_mfma, dim3(NHEADS, NCHUNK, BATCH), dim3(256), 0, stream,
                     xsb, bcb, dtr, alog, Sb, asum);
  hipLaunchKernelGGL(scan_kernel, dim3(NHEADS, BATCH), dim3(256), 0, stream, Sb, asum);
  hipLaunchKernelGGL(yssd_mfma, dim3(NHEADS, NCHUNK, BATCH), dim3(256), 0, stream,
                     xsb, bcb, dtr, alog, dvec, Sb, yb);
  hipLaunchKernelGGL(rmsnorm_kernel, dim3(ROWS), dim3(256), 0, stream, yb, zb, nw);
  hipLaunchKernelGGL(gemm_outproj_mfma, dim3(64, 8), dim3(256), 0, stream, yb, woutB, x, out);
}

// Round 6
// 480.548 us; speedup vs baseline: 4.0139x; 1.0492x over previous
//
#include <hip/hip_runtime.h>
#include <math.h>

#define BATCH   4
#define LSEQ    2048
#define DMODEL  1024
#define DSTATE  128
#define HEADDIM 64
#define DINNER  2048
#define NHEADS  32
#define CONVCH  2304
#define DINPROJ 4384
#define NPAD    4480
#define CHUNKL  128
#define NCHUNK  16
#define ROWS    (BATCH*LSEQ)

// ---------------- workspace layout (BYTE offsets) ----------------
#define B_Z     ((size_t)0)                              // ROWS*DINNER bf16
#define B_XBC   (B_Z   + (size_t)ROWS*DINNER*2)          // ROWS*CONVCH bf16; S aliases first 33.55MB; Wout bf16 aliases tail 4.19MB
#define B_DT    (B_XBC + (size_t)ROWS*CONVCH*2)          // ROWS*NHEADS fp32
#define B_XS    (B_DT  + (size_t)ROWS*NHEADS*4)          // ROWS*DINNER bf16
#define B_BC    (B_XS  + (size_t)ROWS*DINNER*2)          // ROWS*256 bf16
#define B_Y     (B_BC  + (size_t)ROWS*256*2)             // ROWS*DINNER bf16; h bf16 aliases [0,16.8MB); Win bf16 aliases [16.8MB,26MB)
#define B_ASUM  (B_Y   + (size_t)ROWS*DINNER*2)          // BATCH*NCHUNK*NHEADS fp32
#define B_END   (B_ASUM + (size_t)BATCH*NCHUNK*NHEADS*4) // ~137 MB total

typedef __attribute__((ext_vector_type(8))) short bf16x8;
typedef __attribute__((ext_vector_type(4))) float f32x4;

__device__ __forceinline__ float b2f(ushort u) {
  union { uint32_t i; float f; } v; v.i = ((uint32_t)u) << 16; return v.f;
}
__device__ __forceinline__ ushort f2b(float f) {
  union { float f; uint32_t i; } v; v.f = f;
  uint32_t r = (v.i + 0x7FFFu + ((v.i >> 16) & 1u)) >> 16;
  return (ushort)r;
}

__device__ __forceinline__ void async_ld16(const void* g, void* l) {
  __builtin_amdgcn_global_load_lds(
      (const __attribute__((address_space(1))) unsigned int*)g,
      (__attribute__((address_space(3))) unsigned int*)l, 16, 0, 0);
}

// ---------------- shared MFMA GEMM core, BK=64, XOR-swizzled LDS ----------------
// LDS layout: 16B granule g of tile row r lives at slot r*8 + (g ^ (r&7)).
// Staging permutes the GLOBAL address per lane (same 128B row segment -> still
// coalesced); LDS dest stays wave-uniform base + lane*16 (global_load_lds rule).
// Fragment ds_read_b128 bank start = 4*(g^(r&7)) -> uniform over 32 banks.
template<int K>
__device__ __forceinline__ void gemm_core_swz(const ushort* __restrict__ A,
    const ushort* __restrict__ W, int m0, int n0, int tid,
    ushort* lA, ushort* lB, f32x4 acc[4][4])
{
  const int lane = tid & 63;
  const int w = tid >> 6;
  const int wm = (w & 1) * 64;
  const int wn = (w >> 1) * 64;
  const int rl = lane & 15;
  const int q  = lane >> 4;
  for (int k0 = 0; k0 < K; k0 += 64) {
    __syncthreads();
    #pragma unroll
    for (int is = 0; is < 4; is++) {
      int s = (w*4 + is)*64 + lane;
      int row = s >> 3;
      int g = (s & 7) ^ (row & 7);
      async_ld16(A + (size_t)(m0 + row)*K + k0 + g*8, lA + (size_t)s*8);
      async_ld16(W + (size_t)(n0 + row)*K + k0 + g*8, lB + (size_t)s*8);
    }
    __syncthreads();
    #pragma unroll
    for (int kh = 0; kh < 2; kh++) {
      bf16x8 af[4], bfr[4];
      #pragma unroll
      for (int i = 0; i < 4; i++) {
        int row = wm + i*16 + rl;
        af[i] = *(const bf16x8*)&lA[(size_t)(row*8 + ((kh*4 + q) ^ (row & 7)))*8];
      }
      #pragma unroll
      for (int j = 0; j < 4; j++) {
        int row = wn + j*16 + rl;
        bfr[j] = *(const bf16x8*)&lB[(size_t)(row*8 + ((kh*4 + q) ^ (row & 7)))*8];
      }
      #pragma unroll
      for (int i = 0; i < 4; i++)
        #pragma unroll
        for (int j = 0; j < 4; j++)
          acc[i][j] = __builtin_amdgcn_mfma_f32_16x16x32_bf16(af[i], bfr[j], acc[i][j], 0, 0, 0);
    }
  }
}

// ---------------- weight fp32 -> bf16 converters ----------------
__global__ __launch_bounds__(256) void convert_win_kernel(const float* __restrict__ W,
                                                          ushort* __restrict__ Wb)
{
  size_t i = (size_t)blockIdx.x*256 + threadIdx.x;  // grid covers NPAD*DMODEL
  Wb[i] = (i < (size_t)DINPROJ*DMODEL) ? f2b(W[i]) : (ushort)0;
}

__global__ __launch_bounds__(256) void convert_wout_kernel(const float* __restrict__ W,
                                                           ushort* __restrict__ Wb)
{
  size_t i = (size_t)blockIdx.x*256 + threadIdx.x;  // DMODEL*DINNER
  Wb[i] = f2b(W[i]);
}

// ---------------- LayerNorm -> h (bf16) ----------------
__global__ __launch_bounds__(256) void ln_kernel(const float* __restrict__ x,
    const float* __restrict__ w, const float* __restrict__ bias, ushort* __restrict__ h)
{
  const int row = blockIdx.x;
  const int t = threadIdx.x;
  const float* xr = x + (size_t)row * DMODEL;
  float v[4];
  float s = 0.f;
  #pragma unroll
  for (int i = 0; i < 4; i++) { v[i] = xr[t + i*256]; s += v[i]; }
  __shared__ float red[4];
  #pragma unroll
  for (int o = 32; o > 0; o >>= 1) s += __shfl_down(s, o, 64);
  if ((t & 63) == 0) red[t >> 6] = s;
  __syncthreads();
  float mean = (red[0]+red[1]+red[2]+red[3]) * (1.f/DMODEL);
  float vs = 0.f;
  #pragma unroll
  for (int i = 0; i < 4; i++) { float d = v[i]-mean; vs += d*d; }
  #pragma unroll
  for (int o = 32; o > 0; o >>= 1) vs += __shfl_down(vs, o, 64);
  __syncthreads();
  if ((t & 63) == 0) red[t >> 6] = vs;
  __syncthreads();
  float rstd = rsqrtf((red[0]+red[1]+red[2]+red[3]) * (1.f/DMODEL) + 1e-5f);
  ushort* hr = h + (size_t)row * DMODEL;
  #pragma unroll
  for (int i = 0; i < 4; i++) {
    int c = t + i*256;
    hr[c] = f2b((v[i]-mean)*rstd*w[c] + bias[c]);
  }
}

// ---------------- in_proj MFMA GEMM + fused dt softplus ----------------
__global__ __launch_bounds__(256) void gemm_inproj_mfma(const ushort* __restrict__ A,
    const ushort* __restrict__ W, ushort* __restrict__ z, ushort* __restrict__ xbc,
    float* __restrict__ dtr, const float* __restrict__ dtb)
{
  __shared__ ushort smem[128*136];     // 34816B: staging = first 32KB; epilogue restage padded 136
  ushort* lA = smem;
  ushort* lB = smem + 8192;
  const int tid = threadIdx.x;
  const int lane = tid & 63;
  const int w = tid >> 6;
  const int m0 = blockIdx.x * 128;
  const int n0 = blockIdx.y * 128;
  const int wm = (w & 1) * 64;
  const int wn = (w >> 1) * 64;
  f32x4 acc[4][4];
  #pragma unroll
  for (int i = 0; i < 4; i++)
    #pragma unroll
    for (int j = 0; j < 4; j++) acc[i][j] = (f32x4)(0.f);

  gemm_core_swz<DMODEL>(A, W, m0, n0, tid, lA, lB, acc);

  const int col_l = lane & 15;
  const int row_l = (lane >> 4) * 4;
  __syncthreads();   // all frag reads done before smem reuse
  if (n0 < DINNER + CONVCH) {
    #pragma unroll
    for (int i = 0; i < 4; i++)
      #pragma unroll
      for (int j = 0; j < 4; j++)
        #pragma unroll
        for (int r = 0; r < 4; r++)
          smem[(wm + i*16 + row_l + r)*136 + wn + j*16 + col_l] = f2b(acc[i][j][r]);
    __syncthreads();
    ushort* outp; int coff, ncols;
    if (n0 < DINNER) { outp = z;   coff = n0;          ncols = DINNER; }
    else             { outp = xbc; coff = n0 - DINNER; ncols = CONVCH; }
    #pragma unroll
    for (int it = 0; it < 8; it++) {
      int idx = tid + it*256;
      int row = idx >> 4, c8 = idx & 15;
      *(uint4*)(outp + (size_t)(m0 + row)*ncols + coff + c8*8) = *(const uint4*)&smem[row*136 + c8*8];
    }
  } else {
    // dt tile: only local cols [0,32) real (4352..4383); fused softplus(v + bias)
    #pragma unroll
    for (int i = 0; i < 4; i++)
      #pragma unroll
      for (int j = 0; j < 2; j++) {
        int lc = wn + j*16 + col_l;
        if (lc < 32) {
          float bb = dtb[lc];
          #pragma unroll
          for (int r = 0; r < 4; r++) {
            float v = acc[i][j][r] + bb;
            v = (v > 20.f) ? v : log1pf(expf(v));
            dtr[(size_t)(m0 + wm + i*16 + row_l + r)*NHEADS + lc] = v;
          }
        }
      }
  }
}

// ---------------- out_proj MFMA GEMM + residual, LDS-restaged float4 epilogue ----------------
__global__ __launch_bounds__(256) void gemm_outproj_mfma(const ushort* __restrict__ A,
    const ushort* __restrict__ W, const float* __restrict__ x, float* __restrict__ out)
{
  __shared__ ushort smem[17408];       // 34816B >= 33792B (64x132 floats) for restage
  ushort* lA = smem;
  ushort* lB = smem + 8192;
  float* fbuf = (float*)smem;
  const int tid = threadIdx.x;
  const int lane = tid & 63;
  const int w = tid >> 6;
  const int m0 = blockIdx.x * 128;
  const int n0 = blockIdx.y * 128;
  const int wn = (w >> 1) * 64;
  f32x4 acc[4][4];
  #pragma unroll
  for (int i = 0; i < 4; i++)
    #pragma unroll
    for (int j = 0; j < 4; j++) acc[i][j] = (f32x4)(0.f);

  gemm_core_swz<DINNER>(A, W, m0, n0, tid, lA, lB, acc);

  const int colL = lane & 15;
  const int rowQ = (lane >> 4) * 4;
  #pragma unroll
  for (int h0 = 0; h0 < 2; h0++) {
    __syncthreads();   // frag reads (h0=0) / prior copy (h0=1) done
    if ((w & 1) == h0) {
      #pragma unroll
      for (int i = 0; i < 4; i++)
        #pragma unroll
        for (int j = 0; j < 4; j++)
          #pragma unroll
          for (int r = 0; r < 4; r++)
            fbuf[(i*16 + rowQ + r)*132 + wn + j*16 + colL] = acc[i][j][r];
    }
    __syncthreads();
    #pragma unroll
    for (int it = 0; it < 8; it++) {
      int idx = tid + it*256;
      int row = idx >> 5, c4 = idx & 31;
      int gm = m0 + h0*64 + row;
      float4 xv = *(const float4*)(x + (size_t)gm*DMODEL + n0 + c4*4);
      float4 vv = *(const float4*)&fbuf[row*132 + c4*4];
      vv.x += xv.x; vv.y += xv.y; vv.z += xv.z; vv.w += xv.w;
      *(float4*)(out + (size_t)gm*DMODEL + n0 + c4*4) = vv;
    }
  }
}

// ---------------- causal conv4 + SiLU, LDS row-tiled ----------------
__global__ __launch_bounds__(256) void conv_tiled(const ushort* __restrict__ xbc,
    const float* __restrict__ cw, const float* __restrict__ cb,
    ushort* __restrict__ xs, ushort* __restrict__ bcb)
{
  __shared__ ushort tile[35*256];
  const int tid = threadIdx.x;
  const int ch0 = blockIdx.x * 256;
  const int row0 = blockIdx.y * 32;          // never spans a batch boundary (32 | 2048)
  const int l0 = row0 & (LSEQ-1);
  for (int idx = tid; idx < 35*32; idx += 256) {
    int r = idx >> 5, c16 = idx & 31;
    uint4 v = make_uint4(0,0,0,0);
    if (l0 + r - 3 >= 0)
      v = *(const uint4*)(xbc + (size_t)(row0 + r - 3)*CONVCH + ch0 + c16*8);
    *(uint4*)&tile[r*256 + c16*8] = v;
  }
  __syncthreads();
  const int ch = ch0 + tid;
  const float w0 = cw[ch*4+0], w1 = cw[ch*4+1], w2 = cw[ch*4+2], w3 = cw[ch*4+3];
  const float bias = cb[ch];
  const bool isX = (ch0 < DINNER);
  #pragma unroll 4
  for (int r = 0; r < 32; r++) {
    float acc = bias;
    acc = fmaf(b2f(tile[(r+0)*256 + tid]), w0, acc);
    acc = fmaf(b2f(tile[(r+1)*256 + tid]), w1, acc);
    acc = fmaf(b2f(tile[(r+2)*256 + tid]), w2, acc);
    acc = fmaf(b2f(tile[(r+3)*256 + tid]), w3, acc);
    float v = acc / (1.f + expf(-acc));
    if (isX) xs[(size_t)(row0 + r)*DINNER + ch] = f2b(v);
    else     bcb[(size_t)(row0 + r)*256 + (ch - DINNER)] = f2b(v);
  }
}

// ---------------- per-chunk states via MFMA: S[p][n] = sum_l Xw[l][p]*B[l][n] ----------------
__global__ __launch_bounds__(256) void states_mfma(
    const ushort* __restrict__ xs, const ushort* __restrict__ bcb, const float* __restrict__ dt,
    const float* __restrict__ A_log, ushort* __restrict__ S, float* __restrict__ asum)
{
  constexpr int LDP = 136;
  __shared__ ushort lBT[128*LDP];   // B^T[n][l]
  __shared__ ushort lXT[64*LDP];    // Xw^T[p][l]; reused for S restage
  __shared__ float dts[CHUNKL], acs[CHUNKL];
  __shared__ float wtot;
  const int hh = blockIdx.x, c = blockIdx.y, b = blockIdx.z;
  const int tid = threadIdx.x;
  const int lane = tid & 63;
  const int w = tid >> 6;
  const int rbase = b*LSEQ + c*CHUNKL;
  const size_t sbase = (size_t)((b*NCHUNK + c)*NHEADS + hh) * 8192;

  float pre = 0.f;
  if (tid < 128) {
    float myv = dt[(size_t)(rbase + tid)*NHEADS + hh];
    dts[tid] = myv;
    pre = myv;
    #pragma unroll
    for (int o = 1; o < 64; o <<= 1) {
      float u = __shfl_up(pre, o, 64);
      if ((tid & 63) >= o) pre += u;
    }
    if (tid == 63) wtot = pre;
  }
  #pragma unroll
  for (int it = 0; it < 8; it++) {
    int chunk = tid + it*256;
    int l = chunk >> 4, n8 = chunk & 15;
    ushort tmp[8];
    *(uint4*)tmp = *(const uint4*)(bcb + (size_t)(rbase + l)*256 + n8*8);
    #pragma unroll
    for (int u = 0; u < 8; u++) lBT[(n8*8+u)*LDP + l] = tmp[u];
  }
  __syncthreads();
  float alast_loc = 0.f;
  if (tid < 128) {
    float Aval = -expf(A_log[hh]);
    float a = (pre + ((tid >= 64) ? wtot : 0.f)) * Aval;
    acs[tid] = a;
    if (tid == 127) { asum[(b*NCHUNK + c)*NHEADS + hh] = a; }
  }
  __syncthreads();
  alast_loc = acs[CHUNKL-1];
  #pragma unroll
  for (int it = 0; it < 4; it++) {
    int chunk = tid + it*256;
    int l = chunk >> 3, p8 = (chunk & 7)*8;
    ushort tmp[8];
    *(uint4*)tmp = *(const uint4*)(xs + (size_t)(rbase + l)*DINNER + hh*HEADDIM + p8);
    float wl = dts[l] * expf(alast_loc - acs[l]);
    #pragma unroll
    for (int u = 0; u < 8; u++) lXT[(p8+u)*LDP + l] = f2b(b2f(tmp[u]) * wl);
  }
  __syncthreads();

  const int rl = lane & 15;
  const int kq = (lane >> 4) * 8;
  const int nb = w * 32;
  f32x4 acc[4][2];
  #pragma unroll
  for (int i = 0; i < 4; i++) { acc[i][0] = (f32x4)(0.f); acc[i][1] = (f32x4)(0.f); }
  #pragma unroll
  for (int k0 = 0; k0 < 128; k0 += 32) {
    bf16x8 af[4], bfr[2];
    #pragma unroll
    for (int i = 0; i < 4; i++) af[i]  = *(const bf16x8*)&lXT[(i*16 + rl)*LDP + k0 + kq];
    #pragma unroll
    for (int j = 0; j < 2; j++) bfr[j] = *(const bf16x8*)&lBT[(nb + j*16 + rl)*LDP + k0 + kq];
    #pragma unroll
    for (int i = 0; i < 4; i++)
      #pragma unroll
      for (int j = 0; j < 2; j++)
        acc[i][j] = __builtin_amdgcn_mfma_f32_16x16x32_bf16(af[i], bfr[j], acc[i][j], 0, 0, 0);
  }
  __syncthreads();
  const int colL = lane & 15;
  const int rowQ = (lane >> 4) * 4;
  #pragma unroll
  for (int i = 0; i < 4; i++)
    #pragma unroll
    for (int j = 0; j < 2; j++)
      #pragma unroll
      for (int r = 0; r < 4; r++)
        lXT[(i*16 + rowQ + r)*LDP + nb + j*16 + colL] = f2b(acc[i][j][r]);
  __syncthreads();
  #pragma unroll
  for (int it = 0; it < 4; it++) {
    int idx = tid + it*256;
    int row = idx >> 4, c8 = idx & 15;
    *(uint4*)(S + sbase + row*128 + c8*8) = *(const uint4*)&lXT[row*LDP + c8*8];
  }
}

// ---------------- inter-chunk scan, split 4x over state slices ----------------
__global__ __launch_bounds__(256) void scan_kernel(ushort* __restrict__ S, const float* __restrict__ asum)
{
  const int hh = blockIdx.x, sl = blockIdx.y, b = blockIdx.z;
  const int base0 = sl*2048 + threadIdx.x;
  float carry[8];
  #pragma unroll
  for (int i = 0; i < 8; i++) carry[i] = 0.f;
  for (int c = 0; c < NCHUNK; c++) {
    ushort* Sp = S + (size_t)((b*NCHUNK + c)*NHEADS + hh) * 8192;
    float dec = expf(asum[(b*NCHUNK + c)*NHEADS + hh]);
    #pragma unroll
    for (int i = 0; i < 8; i++) {
      int idx = base0 + i*256;
      float sv = b2f(Sp[idx]);
      Sp[idx] = f2b(carry[i]);
      carry[i] = fmaf(dec, carry[i], sv);
    }
  }
}

// ---------------- yssd MFMA: Y = exp(acs)*C.P^T + M.X + D*xs ----------------
__global__ __launch_bounds__(256) void yssd_mfma(
    const ushort* __restrict__ xs, const ushort* __restrict__ bcb, const float* __restrict__ dt,
    const float* __restrict__ A_log, const float* __restrict__ Dvec,
    const ushort* __restrict__ S, ushort* __restrict__ y)
{
  constexpr int LDP = 136;
  __shared__ ushort lC [128*LDP];
  __shared__ ushort lBM[128*LDP];
  __shared__ ushort lP [64*LDP];
  __shared__ ushort lXT[64*LDP];
  __shared__ float dts[CHUNKL], acs[CHUNKL];
  __shared__ float wtot;
  const int hh = blockIdx.x, c = blockIdx.y, b = blockIdx.z;
  const int tid = threadIdx.x;
  const int lane = tid & 63;
  const int w = tid >> 6;
  const int rbase = b*LSEQ + c*CHUNKL;
  const size_t sbase = (size_t)((b*NCHUNK + c)*NHEADS + hh) * 8192;

  #pragma unroll
  for (int it = 0; it < 8; it++) {
    int chunk = tid + it*256;
    int l = chunk >> 4, c8 = chunk & 15;
    const ushort* src = bcb + (size_t)(rbase + l)*256 + c8*8;
    *(uint4*)&lBM[l*LDP + c8*8] = *(const uint4*)src;
    *(uint4*)&lC [l*LDP + c8*8] = *(const uint4*)(src + 128);
  }
  #pragma unroll
  for (int it = 0; it < 4; it++) {
    int chunk = tid + it*256;
    int p = chunk >> 4, c8 = chunk & 15;
    *(uint4*)&lP[p*LDP + c8*8] = *(const uint4*)(S + sbase + p*128 + c8*8);
  }
  #pragma unroll
  for (int it = 0; it < 4; it++) {
    int chunk = tid + it*256;
    int s = chunk >> 3, p0 = (chunk & 7)*8;
    ushort tmp[8];
    *(uint4*)tmp = *(const uint4*)(xs + (size_t)(rbase + s)*DINNER + hh*HEADDIM + p0);
    #pragma unroll
    for (int u = 0; u < 8; u++) lXT[(p0+u)*LDP + s] = tmp[u];
  }
  float pre = 0.f;
  if (tid < 128) {
    float myv = dt[(size_t)(rbase + tid)*NHEADS + hh];
    dts[tid] = myv;
    pre = myv;
    #pragma unroll
    for (int o = 1; o < 64; o <<= 1) {
      float u = __shfl_up(pre, o, 64);
      if ((tid & 63) >= o) pre += u;
    }
    if (tid == 63) wtot = pre;
  }
  __syncthreads();
  if (tid < 128) {
    float Aval = -expf(A_log[hh]);
    acs[tid] = (pre + ((tid >= 64) ? wtot : 0.f)) * Aval;
  }

  const int rl = lane & 15;
  const int kq = (lane >> 4) * 8;
  const int colL = lane & 15;
  const int rowQ = (lane >> 4) * 4;

  const int wm = (w & 1) * 64;
  const int wn = (w >> 1) * 64;
  f32x4 G[4][4];
  #pragma unroll
  for (int i = 0; i < 4; i++)
    #pragma unroll
    for (int j = 0; j < 4; j++) G[i][j] = (f32x4)(0.f);
  #pragma unroll
  for (int k0 = 0; k0 < 128; k0 += 32) {
    bf16x8 af[4], bfr[4];
    #pragma unroll
    for (int i = 0; i < 4; i++) af[i]  = *(const bf16x8*)&lC [(wm + i*16 + rl)*LDP + k0 + kq];
    #pragma unroll
    for (int j = 0; j < 4; j++) bfr[j] = *(const bf16x8*)&lBM[(wn + j*16 + rl)*LDP + k0 + kq];
    #pragma unroll
    for (int i = 0; i < 4; i++)
      #pragma unroll
      for (int j = 0; j < 4; j++)
        G[i][j] = __builtin_amdgcn_mfma_f32_16x16x32_bf16(af[i], bfr[j], G[i][j], 0, 0, 0);
  }
  __syncthreads();

  #pragma unroll
  for (int j = 0; j < 4; j++) {
    int sIdx = wn + j*16 + colL;
    float as = acs[sIdx];
    float ds = dts[sIdx];
    #pragma unroll
    for (int i = 0; i < 4; i++) {
      #pragma unroll
      for (int r = 0; r < 4; r++) {
        int lIdx = wm + i*16 + rowQ + r;
        float m = (lIdx >= sIdx) ? G[i][j][r] * expf(acs[lIdx] - as) * ds : 0.f;
        lBM[lIdx*LDP + sIdx] = f2b(m);
      }
    }
  }

  const int om = w * 32;
  f32x4 Y[2][4];
  #pragma unroll
  for (int i = 0; i < 2; i++)
    #pragma unroll
    for (int j = 0; j < 4; j++) Y[i][j] = (f32x4)(0.f);
  #pragma unroll
  for (int k0 = 0; k0 < 128; k0 += 32) {
    bf16x8 a2[2], b2[4];
    #pragma unroll
    for (int i = 0; i < 2; i++) a2[i] = *(const bf16x8*)&lC[(om + i*16 + rl)*LDP + k0 + kq];
    #pragma unroll
    for (int j = 0; j < 4; j++) b2[j] = *(const bf16x8*)&lP[(j*16 + rl)*LDP + k0 + kq];
    #pragma unroll
    for (int i = 0; i < 2; i++)
      #pragma unroll
      for (int j = 0; j < 4; j++)
        Y[i][j] = __builtin_amdgcn_mfma_f32_16x16x32_bf16(a2[i], b2[j], Y[i][j], 0, 0, 0);
  }
  #pragma unroll
  for (int i = 0; i < 2; i++)
    #pragma unroll
    for (int r = 0; r < 4; r++) {
      float e = expf(acs[om + i*16 + rowQ + r]);
      #pragma unroll
      for (int j = 0; j < 4; j++) Y[i][j][r] *= e;
    }
  __syncthreads();

  #pragma unroll
  for (int k0 = 0; k0 < 128; k0 += 32) {
    bf16x8 a3[2], b3[4];
    #pragma unroll
    for (int i = 0; i < 2; i++) a3[i] = *(const bf16x8*)&lBM[(om + i*16 + rl)*LDP + k0 + kq];
    #pragma unroll
    for (int j = 0; j < 4; j++) b3[j] = *(const bf16x8*)&lXT[(j*16 + rl)*LDP + k0 + kq];
    #pragma unroll
    for (int i = 0; i < 2; i++)
      #pragma unroll
      for (int j = 0; j < 4; j++)
        Y[i][j] = __builtin_amdgcn_mfma_f32_16x16x32_bf16(a3[i], b3[j], Y[i][j], 0, 0, 0);
  }

  const float Dh = Dvec[hh];
  #pragma unroll
  for (int i = 0; i < 2; i++) {
    #pragma unroll
    for (int r = 0; r < 4; r++) {
      int lIdx = om + i*16 + rowQ + r;
      ushort* yrow = y + (size_t)(rbase + lIdx)*DINNER + hh*HEADDIM;
      #pragma unroll
      for (int j = 0; j < 4; j++) {
        int p = j*16 + colL;
        float val = Y[i][j][r] + Dh * b2f(lXT[p*LDP + lIdx]);
        yrow[p] = f2b(val);
      }
    }
  }
}

// ---------------- gated RMSNorm (in place on y, bf16) ----------------
__global__ __launch_bounds__(256) void rmsnorm_kernel(ushort* __restrict__ y,
    const ushort* __restrict__ z, const float* __restrict__ nw)
{
  const int row = blockIdx.x;
  const int t = threadIdx.x;
  ushort* yr = y + (size_t)row*DINNER;
  const ushort* zr = z + (size_t)row*DINNER;
  float v[8];
  float ss = 0.f;
  #pragma unroll
  for (int i = 0; i < 8; i++) {
    int c = t + i*256;
    float zz = b2f(zr[c]);
    float g = b2f(yr[c]) * (zz / (1.f + expf(-zz)));
    v[i] = g;
    ss += g*g;
  }
  #pragma unroll
  for (int o = 32; o > 0; o >>= 1) ss += __shfl_down(ss, o, 64);
  __shared__ float red[4];
  if ((t & 63) == 0) red[t >> 6] = ss;
  __syncthreads();
  float scale = rsqrtf((red[0]+red[1]+red[2]+red[3]) * (1.f/DINNER) + 1e-5f);
  #pragma unroll
  for (int i = 0; i < 8; i++) {
    int c = t + i*256;
    yr[c] = f2b(v[i]*scale*nw[c]);
  }
}

extern "C" void kernel_launch(void* const* d_in, const int* in_sizes, int n_in,
                              void* d_out, int out_size, void* d_ws, size_t ws_size,
                              hipStream_t stream)
{
  const float* x    = (const float*)d_in[0];
  const float* lnw  = (const float*)d_in[1];
  const float* lnb  = (const float*)d_in[2];
  const float* win  = (const float*)d_in[3];
  const float* cw   = (const float*)d_in[4];
  const float* cb   = (const float*)d_in[5];
  const float* dtb  = (const float*)d_in[6];
  const float* alog = (const float*)d_in[7];
  const float* dvec = (const float*)d_in[8];
  const float* nw   = (const float*)d_in[9];
  const float* wout = (const float*)d_in[10];
  float* out = (float*)d_out;
  char* ws = (char*)d_ws;
  (void)in_sizes; (void)n_in; (void)out_size;

  if (ws_size < B_END) return;  // workspace too small: fail cleanly, don't fault

  ushort* zb   = (ushort*)(ws + B_Z);
  ushort* xbcb = (ushort*)(ws + B_XBC);
  float*  dtr  = (float*) (ws + B_DT);
  ushort* xsb  = (ushort*)(ws + B_XS);
  ushort* bcb  = (ushort*)(ws + B_BC);
  ushort* yb   = (ushort*)(ws + B_Y);
  float*  asum = (float*) (ws + B_ASUM);
  ushort* Sb   = xbcb;                                        // aliases xbc (dead after conv)
  ushort* hb   = yb;                                          // aliases y[0 : 16.8MB]
  ushort* winB = (ushort*)(ws + B_Y + (size_t)ROWS*DMODEL*2); // aliases y[16.8MB : 26MB]
  ushort* woutB= (ushort*)(ws + B_XBC + (size_t)BATCH*NCHUNK*NHEADS*HEADDIM*DSTATE*2); // XBC tail (4.19MB)

  hipLaunchKernelGGL(convert_win_kernel, dim3((NPAD*DMODEL)/256), dim3(256), 0, stream, win, winB);
  hipLaunchKernelGGL(ln_kernel, dim3(ROWS), dim3(256), 0, stream, x, lnw, lnb, hb);
  hipLaunchKernelGGL(gemm_inproj_mfma, dim3(64, 35), dim3(256), 0, stream, hb, winB, zb, xbcb, dtr, dtb);
  hipLaunchKernelGGL(conv_tiled, dim3(9, ROWS/32), dim3(256), 0, stream, xbcb, cw, cb, xsb, bcb);
  hipLaunchKernelGGL(convert_wout_kernel, dim3((DMODEL*DINNER)/256), dim3(256), 0, stream, wout, woutB);
  hipLaunchKernelGGL(states_mfma, dim3(NHEADS, NCHUNK, BATCH), dim3(256), 0, stream,
                     xsb, bcb, dtr, alog, Sb, asum);
  hipLaunchKernelGGL(scan_kernel, dim3(NHEADS, 4, BATCH), dim3(256), 0, stream, Sb, asum);
  hipLaunchKernelGGL(yssd_mfma, dim3(NHEADS, NCHUNK, BATCH), dim3(256), 0, stream,
                     xsb, bcb, dtr, alog, dvec, Sb, yb);
  hipLaunchKernelGGL(rmsnorm_kernel, dim3(ROWS), dim3(256), 0, stream, yb, zb, nw);
  hipLaunchKernelGGL(gemm_outproj_mfma, dim3(64, 8), dim3(256), 0, stream, yb, woutB, x, out);
}

// Round 7
// 459.623 us; speedup vs baseline: 4.1967x; 1.0455x over previous
//
#include <hip/hip_runtime.h>
#include <math.h>

#define BATCH   4
#define LSEQ    2048
#define DMODEL  1024
#define DSTATE  128
#define HEADDIM 64
#define DINNER  2048
#define NHEADS  32
#define CONVCH  2304
#define DINPROJ 4384
#define NPAD    4480
#define CHUNKL  128
#define NCHUNK  16
#define ROWS    (BATCH*LSEQ)

// ---------------- workspace layout (BYTE offsets) ----------------
#define B_Z     ((size_t)0)                              // ROWS*DINNER bf16
#define B_XBC   (B_Z   + (size_t)ROWS*DINNER*2)          // ROWS*CONVCH bf16; S aliases first 33.55MB; Wout bf16 aliases tail 4.19MB
#define B_DT    (B_XBC + (size_t)ROWS*CONVCH*2)          // ROWS*NHEADS fp32
#define B_XS    (B_DT  + (size_t)ROWS*NHEADS*4)          // ROWS*DINNER bf16
#define B_BC    (B_XS  + (size_t)ROWS*DINNER*2)          // ROWS*256 bf16
#define B_Y     (B_BC  + (size_t)ROWS*256*2)             // ROWS*DINNER bf16; h bf16 aliases [0,16.8MB); Win bf16 aliases [16.8MB,26MB)
#define B_ASUM  (B_Y   + (size_t)ROWS*DINNER*2)          // BATCH*NCHUNK*NHEADS fp32
#define B_END   (B_ASUM + (size_t)BATCH*NCHUNK*NHEADS*4) // ~137 MB total

typedef __attribute__((ext_vector_type(8))) short bf16x8;
typedef __attribute__((ext_vector_type(4))) float f32x4;

__device__ __forceinline__ float b2f(ushort u) {
  union { uint32_t i; float f; } v; v.i = ((uint32_t)u) << 16; return v.f;
}
__device__ __forceinline__ ushort f2b(float f) {
  union { float f; uint32_t i; } v; v.f = f;
  uint32_t r = (v.i + 0x7FFFu + ((v.i >> 16) & 1u)) >> 16;
  return (ushort)r;
}

__device__ __forceinline__ void async_ld16(const void* g, void* l) {
  __builtin_amdgcn_global_load_lds(
      (const __attribute__((address_space(1))) unsigned int*)g,
      (__attribute__((address_space(3))) unsigned int*)l, 16, 0, 0);
}

// ---------------- shared MFMA GEMM core, BK=64, XOR-swizzled LDS ----------------
// LDS layout: 16B granule g of tile row r lives at slot r*8 + (g ^ (r&7)).
template<int K>
__device__ __forceinline__ void gemm_core_swz(const ushort* __restrict__ A,
    const ushort* __restrict__ W, int m0, int n0, int tid,
    ushort* lA, ushort* lB, f32x4 acc[4][4])
{
  const int lane = tid & 63;
  const int w = tid >> 6;
  const int wm = (w & 1) * 64;
  const int wn = (w >> 1) * 64;
  const int rl = lane & 15;
  const int q  = lane >> 4;
  for (int k0 = 0; k0 < K; k0 += 64) {
    __syncthreads();
    #pragma unroll
    for (int is = 0; is < 4; is++) {
      int s = (w*4 + is)*64 + lane;
      int row = s >> 3;
      int g = (s & 7) ^ (row & 7);
      async_ld16(A + (size_t)(m0 + row)*K + k0 + g*8, lA + (size_t)s*8);
      async_ld16(W + (size_t)(n0 + row)*K + k0 + g*8, lB + (size_t)s*8);
    }
    __syncthreads();
    #pragma unroll
    for (int kh = 0; kh < 2; kh++) {
      bf16x8 af[4], bfr[4];
      #pragma unroll
      for (int i = 0; i < 4; i++) {
        int row = wm + i*16 + rl;
        af[i] = *(const bf16x8*)&lA[(size_t)(row*8 + ((kh*4 + q) ^ (row & 7)))*8];
      }
      #pragma unroll
      for (int j = 0; j < 4; j++) {
        int row = wn + j*16 + rl;
        bfr[j] = *(const bf16x8*)&lB[(size_t)(row*8 + ((kh*4 + q) ^ (row & 7)))*8];
      }
      #pragma unroll
      for (int i = 0; i < 4; i++)
        #pragma unroll
        for (int j = 0; j < 4; j++)
          acc[i][j] = __builtin_amdgcn_mfma_f32_16x16x32_bf16(af[i], bfr[j], acc[i][j], 0, 0, 0);
    }
  }
}

// ---------------- weight fp32 -> bf16 converters ----------------
__global__ __launch_bounds__(256) void convert_win_kernel(const float* __restrict__ W,
                                                          ushort* __restrict__ Wb)
{
  size_t i = (size_t)blockIdx.x*256 + threadIdx.x;
  Wb[i] = (i < (size_t)DINPROJ*DMODEL) ? f2b(W[i]) : (ushort)0;
}

__global__ __launch_bounds__(256) void convert_wout_kernel(const float* __restrict__ W,
                                                           ushort* __restrict__ Wb)
{
  size_t i = (size_t)blockIdx.x*256 + threadIdx.x;
  Wb[i] = f2b(W[i]);
}

// ---------------- LayerNorm -> h (bf16) ----------------
__global__ __launch_bounds__(256) void ln_kernel(const float* __restrict__ x,
    const float* __restrict__ w, const float* __restrict__ bias, ushort* __restrict__ h)
{
  const int row = blockIdx.x;
  const int t = threadIdx.x;
  const float* xr = x + (size_t)row * DMODEL;
  float v[4];
  float s = 0.f;
  #pragma unroll
  for (int i = 0; i < 4; i++) { v[i] = xr[t + i*256]; s += v[i]; }
  __shared__ float red[4];
  #pragma unroll
  for (int o = 32; o > 0; o >>= 1) s += __shfl_down(s, o, 64);
  if ((t & 63) == 0) red[t >> 6] = s;
  __syncthreads();
  float mean = (red[0]+red[1]+red[2]+red[3]) * (1.f/DMODEL);
  float vs = 0.f;
  #pragma unroll
  for (int i = 0; i < 4; i++) { float d = v[i]-mean; vs += d*d; }
  #pragma unroll
  for (int o = 32; o > 0; o >>= 1) vs += __shfl_down(vs, o, 64);
  __syncthreads();
  if ((t & 63) == 0) red[t >> 6] = vs;
  __syncthreads();
  float rstd = rsqrtf((red[0]+red[1]+red[2]+red[3]) * (1.f/DMODEL) + 1e-5f);
  ushort* hr = h + (size_t)row * DMODEL;
  #pragma unroll
  for (int i = 0; i < 4; i++) {
    int c = t + i*256;
    hr[c] = f2b((v[i]-mean)*rstd*w[c] + bias[c]);
  }
}

// ---------------- in_proj MFMA GEMM + fused dt softplus (32KB LDS) ----------------
__global__ __launch_bounds__(256) void gemm_inproj_mfma(const ushort* __restrict__ A,
    const ushort* __restrict__ W, ushort* __restrict__ z, ushort* __restrict__ xbc,
    float* __restrict__ dtr, const float* __restrict__ dtb)
{
  __shared__ ushort smem[16384];       // 32 KB: staging (2x16KB) OR swizzled 128x128 restage
  ushort* lA = smem;
  ushort* lB = smem + 8192;
  const int tid = threadIdx.x;
  const int lane = tid & 63;
  const int w = tid >> 6;
  const int m0 = blockIdx.x * 128;
  const int n0 = blockIdx.y * 128;
  const int wm = (w & 1) * 64;
  const int wn = (w >> 1) * 64;
  f32x4 acc[4][4];
  #pragma unroll
  for (int i = 0; i < 4; i++)
    #pragma unroll
    for (int j = 0; j < 4; j++) acc[i][j] = (f32x4)(0.f);

  gemm_core_swz<DMODEL>(A, W, m0, n0, tid, lA, lB, acc);

  const int col_l = lane & 15;
  const int row_l = (lane >> 4) * 4;
  __syncthreads();   // all frag reads done before smem reuse
  if (n0 < DINNER + CONVCH) {
    // swizzled restage: granule g of row r at r*128 + ((g ^ (r&7))<<3)
    #pragma unroll
    for (int i = 0; i < 4; i++)
      #pragma unroll
      for (int j = 0; j < 4; j++) {
        int col = wn + j*16 + col_l;
        int g = col >> 3;
        #pragma unroll
        for (int r = 0; r < 4; r++) {
          int row = wm + i*16 + row_l + r;
          smem[row*128 + ((g ^ (row & 7)) << 3) + (col & 7)] = f2b(acc[i][j][r]);
        }
      }
    __syncthreads();
    ushort* outp; int coff, ncols;
    if (n0 < DINNER) { outp = z;   coff = n0;          ncols = DINNER; }
    else             { outp = xbc; coff = n0 - DINNER; ncols = CONVCH; }
    #pragma unroll
    for (int it = 0; it < 8; it++) {
      int idx = tid + it*256;
      int row = idx >> 4, c8 = idx & 15;
      *(uint4*)(outp + (size_t)(m0 + row)*ncols + coff + c8*8) =
          *(const uint4*)&smem[row*128 + ((c8 ^ (row & 7)) << 3)];
    }
  } else {
    // dt tile: only local cols [0,32) real; fused softplus(v + bias)
    #pragma unroll
    for (int i = 0; i < 4; i++)
      #pragma unroll
      for (int j = 0; j < 2; j++) {
        int lc = wn + j*16 + col_l;
        if (lc < 32) {
          float bb = dtb[lc];
          #pragma unroll
          for (int r = 0; r < 4; r++) {
            float v = acc[i][j][r] + bb;
            v = (v > 20.f) ? v : log1pf(expf(v));
            dtr[(size_t)(m0 + wm + i*16 + row_l + r)*NHEADS + lc] = v;
          }
        }
      }
  }
}

// ---------------- out_proj MFMA GEMM + residual (32KB LDS, swizzled fp32 restage) ----------------
__global__ __launch_bounds__(256) void gemm_outproj_mfma(const ushort* __restrict__ A,
    const ushort* __restrict__ W, const float* __restrict__ x, float* __restrict__ out)
{
  __shared__ ushort smem[16384];       // 32 KB: staging OR 64x128 fp32 restage
  ushort* lA = smem;
  ushort* lB = smem + 8192;
  float* fbuf = (float*)smem;
  const int tid = threadIdx.x;
  const int lane = tid & 63;
  const int w = tid >> 6;
  const int m0 = blockIdx.x * 128;
  const int n0 = blockIdx.y * 128;
  const int wn = (w >> 1) * 64;
  f32x4 acc[4][4];
  #pragma unroll
  for (int i = 0; i < 4; i++)
    #pragma unroll
    for (int j = 0; j < 4; j++) acc[i][j] = (f32x4)(0.f);

  gemm_core_swz<DINNER>(A, W, m0, n0, tid, lA, lB, acc);

  const int colL = lane & 15;
  const int rowQ = (lane >> 4) * 4;
  #pragma unroll
  for (int h0 = 0; h0 < 2; h0++) {
    __syncthreads();
    if ((w & 1) == h0) {
      #pragma unroll
      for (int i = 0; i < 4; i++)
        #pragma unroll
        for (int j = 0; j < 4; j++) {
          int col = wn + j*16 + colL;
          int g = col >> 2;
          #pragma unroll
          for (int r = 0; r < 4; r++) {
            int row = i*16 + rowQ + r;
            fbuf[row*128 + ((g ^ (row & 7)) << 2) + (col & 3)] = acc[i][j][r];
          }
        }
    }
    __syncthreads();
    #pragma unroll
    for (int it = 0; it < 8; it++) {
      int idx = tid + it*256;
      int row = idx >> 5, c4 = idx & 31;
      int gm = m0 + h0*64 + row;
      float4 xv = *(const float4*)(x + (size_t)gm*DMODEL + n0 + c4*4);
      float4 vv = *(const float4*)&fbuf[row*128 + ((c4 ^ (row & 7)) << 2)];
      vv.x += xv.x; vv.y += xv.y; vv.z += xv.z; vv.w += xv.w;
      *(float4*)(out + (size_t)gm*DMODEL + n0 + c4*4) = vv;
    }
  }
}

// ---------------- causal conv4 + SiLU, LDS row-tiled ----------------
__global__ __launch_bounds__(256) void conv_tiled(const ushort* __restrict__ xbc,
    const float* __restrict__ cw, const float* __restrict__ cb,
    ushort* __restrict__ xs, ushort* __restrict__ bcb)
{
  __shared__ ushort tile[35*256];
  const int tid = threadIdx.x;
  const int ch0 = blockIdx.x * 256;
  const int row0 = blockIdx.y * 32;
  const int l0 = row0 & (LSEQ-1);
  for (int idx = tid; idx < 35*32; idx += 256) {
    int r = idx >> 5, c16 = idx & 31;
    uint4 v = make_uint4(0,0,0,0);
    if (l0 + r - 3 >= 0)
      v = *(const uint4*)(xbc + (size_t)(row0 + r - 3)*CONVCH + ch0 + c16*8);
    *(uint4*)&tile[r*256 + c16*8] = v;
  }
  __syncthreads();
  const int ch = ch0 + tid;
  const float w0 = cw[ch*4+0], w1 = cw[ch*4+1], w2 = cw[ch*4+2], w3 = cw[ch*4+3];
  const float bias = cb[ch];
  const bool isX = (ch0 < DINNER);
  #pragma unroll 4
  for (int r = 0; r < 32; r++) {
    float acc = bias;
    acc = fmaf(b2f(tile[(r+0)*256 + tid]), w0, acc);
    acc = fmaf(b2f(tile[(r+1)*256 + tid]), w1, acc);
    acc = fmaf(b2f(tile[(r+2)*256 + tid]), w2, acc);
    acc = fmaf(b2f(tile[(r+3)*256 + tid]), w3, acc);
    float v = acc / (1.f + expf(-acc));
    if (isX) xs[(size_t)(row0 + r)*DINNER + ch] = f2b(v);
    else     bcb[(size_t)(row0 + r)*256 + (ch - DINNER)] = f2b(v);
  }
}

// ---------------- per-chunk states via MFMA: S[p][n] = sum_l Xw[l][p]*B[l][n] ----------------
__global__ __launch_bounds__(256) void states_mfma(
    const ushort* __restrict__ xs, const ushort* __restrict__ bcb, const float* __restrict__ dt,
    const float* __restrict__ A_log, ushort* __restrict__ S, float* __restrict__ asum)
{
  constexpr int LDP = 136;
  __shared__ ushort lBT[128*LDP];   // B^T[n][l]
  __shared__ ushort lXT[64*LDP];    // Xw^T[p][l]; reused for S restage
  __shared__ float dts[CHUNKL], acs[CHUNKL];
  __shared__ float wtot;
  const int hh = blockIdx.x, c = blockIdx.y, b = blockIdx.z;
  const int tid = threadIdx.x;
  const int lane = tid & 63;
  const int w = tid >> 6;
  const int rbase = b*LSEQ + c*CHUNKL;
  const size_t sbase = (size_t)((b*NCHUNK + c)*NHEADS + hh) * 8192;

  float pre = 0.f;
  if (tid < 128) {
    float myv = dt[(size_t)(rbase + tid)*NHEADS + hh];
    dts[tid] = myv;
    pre = myv;
    #pragma unroll
    for (int o = 1; o < 64; o <<= 1) {
      float u = __shfl_up(pre, o, 64);
      if ((tid & 63) >= o) pre += u;
    }
    if (tid == 63) wtot = pre;
  }
  #pragma unroll
  for (int it = 0; it < 8; it++) {
    int chunk = tid + it*256;
    int l = chunk >> 4, n8 = chunk & 15;
    ushort tmp[8];
    *(uint4*)tmp = *(const uint4*)(bcb + (size_t)(rbase + l)*256 + n8*8);
    #pragma unroll
    for (int u = 0; u < 8; u++) lBT[(n8*8+u)*LDP + l] = tmp[u];
  }
  __syncthreads();
  float alast_loc = 0.f;
  if (tid < 128) {
    float Aval = -expf(A_log[hh]);
    float a = (pre + ((tid >= 64) ? wtot : 0.f)) * Aval;
    acs[tid] = a;
    if (tid == 127) { asum[(b*NCHUNK + c)*NHEADS + hh] = a; }
  }
  __syncthreads();
  alast_loc = acs[CHUNKL-1];
  #pragma unroll
  for (int it = 0; it < 4; it++) {
    int chunk = tid + it*256;
    int l = chunk >> 3, p8 = (chunk & 7)*8;
    ushort tmp[8];
    *(uint4*)tmp = *(const uint4*)(xs + (size_t)(rbase + l)*DINNER + hh*HEADDIM + p8);
    float wl = dts[l] * expf(alast_loc - acs[l]);
    #pragma unroll
    for (int u = 0; u < 8; u++) lXT[(p8+u)*LDP + l] = f2b(b2f(tmp[u]) * wl);
  }
  __syncthreads();

  const int rl = lane & 15;
  const int kq = (lane >> 4) * 8;
  const int nb = w * 32;
  f32x4 acc[4][2];
  #pragma unroll
  for (int i = 0; i < 4; i++) { acc[i][0] = (f32x4)(0.f); acc[i][1] = (f32x4)(0.f); }
  #pragma unroll
  for (int k0 = 0; k0 < 128; k0 += 32) {
    bf16x8 af[4], bfr[2];
    #pragma unroll
    for (int i = 0; i < 4; i++) af[i]  = *(const bf16x8*)&lXT[(i*16 + rl)*LDP + k0 + kq];
    #pragma unroll
    for (int j = 0; j < 2; j++) bfr[j] = *(const bf16x8*)&lBT[(nb + j*16 + rl)*LDP + k0 + kq];
    #pragma unroll
    for (int i = 0; i < 4; i++)
      #pragma unroll
      for (int j = 0; j < 2; j++)
        acc[i][j] = __builtin_amdgcn_mfma_f32_16x16x32_bf16(af[i], bfr[j], acc[i][j], 0, 0, 0);
  }
  __syncthreads();
  const int colL = lane & 15;
  const int rowQ = (lane >> 4) * 4;
  #pragma unroll
  for (int i = 0; i < 4; i++)
    #pragma unroll
    for (int j = 0; j < 2; j++)
      #pragma unroll
      for (int r = 0; r < 4; r++)
        lXT[(i*16 + rowQ + r)*LDP + nb + j*16 + colL] = f2b(acc[i][j][r]);
  __syncthreads();
  #pragma unroll
  for (int it = 0; it < 4; it++) {
    int idx = tid + it*256;
    int row = idx >> 4, c8 = idx & 15;
    *(uint4*)(S + sbase + row*128 + c8*8) = *(const uint4*)&lXT[row*LDP + c8*8];
  }
}

// ---------------- inter-chunk scan, split 4x over state slices ----------------
__global__ __launch_bounds__(256) void scan_kernel(ushort* __restrict__ S, const float* __restrict__ asum)
{
  const int hh = blockIdx.x, sl = blockIdx.y, b = blockIdx.z;
  const int base0 = sl*2048 + threadIdx.x;
  float carry[8];
  #pragma unroll
  for (int i = 0; i < 8; i++) carry[i] = 0.f;
  for (int c = 0; c < NCHUNK; c++) {
    ushort* Sp = S + (size_t)((b*NCHUNK + c)*NHEADS + hh) * 8192;
    float dec = expf(asum[(b*NCHUNK + c)*NHEADS + hh]);
    #pragma unroll
    for (int i = 0; i < 8; i++) {
      int idx = base0 + i*256;
      float sv = b2f(Sp[idx]);
      Sp[idx] = f2b(carry[i]);
      carry[i] = fmaf(dec, carry[i], sv);
    }
  }
}

// ---------------- yssd MFMA v2: direct-global fragments for C/B/P; LDS only M + X^T ----------------
__global__ __launch_bounds__(256) void yssd_mfma(
    const ushort* __restrict__ xs, const ushort* __restrict__ bcb, const float* __restrict__ dt,
    const float* __restrict__ A_log, const float* __restrict__ Dvec,
    const ushort* __restrict__ S, ushort* __restrict__ y)
{
  constexpr int LDP = 136;
  __shared__ ushort lM [128*LDP];   // M[l][s]
  __shared__ ushort lXT[64*LDP];    // X^T[p][s]
  __shared__ float dts[CHUNKL], acs[CHUNKL];
  __shared__ float wtot;
  const int hh = blockIdx.x, c = blockIdx.y, b = blockIdx.z;
  const int tid = threadIdx.x;
  const int lane = tid & 63;
  const int w = tid >> 6;
  const int rbase = b*LSEQ + c*CHUNKL;
  const size_t sbase = (size_t)((b*NCHUNK + c)*NHEADS + hh) * 8192;
  const ushort* Bg = bcb + (size_t)rbase*256;        // B row s at Bg + s*256
  const ushort* Cg = Bg + 128;                       // C row l at Cg + l*256

  // stage X^T (transposing scatter) — the only global->LDS staging
  #pragma unroll
  for (int it = 0; it < 4; it++) {
    int chunk = tid + it*256;
    int s = chunk >> 3, p0 = (chunk & 7)*8;
    ushort tmp[8];
    *(uint4*)tmp = *(const uint4*)(xs + (size_t)(rbase + s)*DINNER + hh*HEADDIM + p0);
    #pragma unroll
    for (int u = 0; u < 8; u++) lXT[(p0+u)*LDP + s] = tmp[u];
  }
  // dt load + wave-parallel inclusive scan
  float pre = 0.f;
  if (tid < 128) {
    float myv = dt[(size_t)(rbase + tid)*NHEADS + hh];
    dts[tid] = myv;
    pre = myv;
    #pragma unroll
    for (int o = 1; o < 64; o <<= 1) {
      float u = __shfl_up(pre, o, 64);
      if ((tid & 63) >= o) pre += u;
    }
    if (tid == 63) wtot = pre;
  }
  __syncthreads();
  if (tid < 128) {
    float Aval = -expf(A_log[hh]);
    acs[tid] = (pre + ((tid >= 64) ? wtot : 0.f)) * Aval;
  }

  const int rl = lane & 15;
  const int kq = (lane >> 4) * 8;
  const int colL = lane & 15;
  const int rowQ = (lane >> 4) * 4;

  // ---- GEMM1: G[l][s] = sum_n C[l][n]*B[s][n], fragments direct from global
  const int wm = (w & 1) * 64;
  const int wn = (w >> 1) * 64;
  f32x4 G[4][4];
  #pragma unroll
  for (int i = 0; i < 4; i++)
    #pragma unroll
    for (int j = 0; j < 4; j++) G[i][j] = (f32x4)(0.f);
  #pragma unroll
  for (int k0 = 0; k0 < 128; k0 += 32) {
    bf16x8 af[4], bfr[4];
    #pragma unroll
    for (int i = 0; i < 4; i++) af[i]  = *(const bf16x8*)(Cg + (size_t)(wm + i*16 + rl)*256 + k0 + kq);
    #pragma unroll
    for (int j = 0; j < 4; j++) bfr[j] = *(const bf16x8*)(Bg + (size_t)(wn + j*16 + rl)*256 + k0 + kq);
    #pragma unroll
    for (int i = 0; i < 4; i++)
      #pragma unroll
      for (int j = 0; j < 4; j++)
        G[i][j] = __builtin_amdgcn_mfma_f32_16x16x32_bf16(af[i], bfr[j], G[i][j], 0, 0, 0);
  }
  __syncthreads();   // acs (written pre-GEMM1 by tid<128) visible to all; XT staged

  // ---- M[l][s] = (l>=s) ? G*exp(acs[l]-acs[s])*dt[s] : 0  -> lM
  #pragma unroll
  for (int j = 0; j < 4; j++) {
    int sIdx = wn + j*16 + colL;
    float as = acs[sIdx];
    float ds = dts[sIdx];
    #pragma unroll
    for (int i = 0; i < 4; i++) {
      #pragma unroll
      for (int r = 0; r < 4; r++) {
        int lIdx = wm + i*16 + rowQ + r;
        float m = (lIdx >= sIdx) ? G[i][j][r] * expf(acs[lIdx] - as) * ds : 0.f;
        lM[lIdx*LDP + sIdx] = f2b(m);
      }
    }
  }

  // ---- GEMM-off: Y[l][p] = sum_n C[l][n]*P[p][n], C and P direct from global
  const int om = w * 32;
  f32x4 Y[2][4];
  #pragma unroll
  for (int i = 0; i < 2; i++)
    #pragma unroll
    for (int j = 0; j < 4; j++) Y[i][j] = (f32x4)(0.f);
  #pragma unroll
  for (int k0 = 0; k0 < 128; k0 += 32) {
    bf16x8 a2[2], b2[4];
    #pragma unroll
    for (int i = 0; i < 2; i++) a2[i] = *(const bf16x8*)(Cg + (size_t)(om + i*16 + rl)*256 + k0 + kq);
    #pragma unroll
    for (int j = 0; j < 4; j++) b2[j] = *(const bf16x8*)(S + sbase + (size_t)(j*16 + rl)*128 + k0 + kq);
    #pragma unroll
    for (int i = 0; i < 2; i++)
      #pragma unroll
      for (int j = 0; j < 4; j++)
        Y[i][j] = __builtin_amdgcn_mfma_f32_16x16x32_bf16(a2[i], b2[j], Y[i][j], 0, 0, 0);
  }
  #pragma unroll
  for (int i = 0; i < 2; i++)
    #pragma unroll
    for (int r = 0; r < 4; r++) {
      float e = expf(acs[om + i*16 + rowQ + r]);
      #pragma unroll
      for (int j = 0; j < 4; j++) Y[i][j][r] *= e;
    }
  __syncthreads();   // lM writes visible

  // ---- GEMM-diag: Y[l][p] += sum_s M[l][s]*XT[p][s]
  #pragma unroll
  for (int k0 = 0; k0 < 128; k0 += 32) {
    bf16x8 a3[2], b3[4];
    #pragma unroll
    for (int i = 0; i < 2; i++) a3[i] = *(const bf16x8*)&lM[(om + i*16 + rl)*LDP + k0 + kq];
    #pragma unroll
    for (int j = 0; j < 4; j++) b3[j] = *(const bf16x8*)&lXT[(j*16 + rl)*LDP + k0 + kq];
    #pragma unroll
    for (int i = 0; i < 2; i++)
      #pragma unroll
      for (int j = 0; j < 4; j++)
        Y[i][j] = __builtin_amdgcn_mfma_f32_16x16x32_bf16(a3[i], b3[j], Y[i][j], 0, 0, 0);
  }

  // ---- epilogue: += D*xs, write bf16
  const float Dh = Dvec[hh];
  #pragma unroll
  for (int i = 0; i < 2; i++) {
    #pragma unroll
    for (int r = 0; r < 4; r++) {
      int lIdx = om + i*16 + rowQ + r;
      ushort* yrow = y + (size_t)(rbase + lIdx)*DINNER + hh*HEADDIM;
      #pragma unroll
      for (int j = 0; j < 4; j++) {
        int p = j*16 + colL;
        float val = Y[i][j][r] + Dh * b2f(lXT[p*LDP + lIdx]);
        yrow[p] = f2b(val);
      }
    }
  }
}

// ---------------- gated RMSNorm (in place on y, bf16) ----------------
__global__ __launch_bounds__(256) void rmsnorm_kernel(ushort* __restrict__ y,
    const ushort* __restrict__ z, const float* __restrict__ nw)
{
  const int row = blockIdx.x;
  const int t = threadIdx.x;
  ushort* yr = y + (size_t)row*DINNER;
  const ushort* zr = z + (size_t)row*DINNER;
  float v[8];
  float ss = 0.f;
  #pragma unroll
  for (int i = 0; i < 8; i++) {
    int c = t + i*256;
    float zz = b2f(zr[c]);
    float g = b2f(yr[c]) * (zz / (1.f + expf(-zz)));
    v[i] = g;
    ss += g*g;
  }
  #pragma unroll
  for (int o = 32; o > 0; o >>= 1) ss += __shfl_down(ss, o, 64);
  __shared__ float red[4];
  if ((t & 63) == 0) red[t >> 6] = ss;
  __syncthreads();
  float scale = rsqrtf((red[0]+red[1]+red[2]+red[3]) * (1.f/DINNER) + 1e-5f);
  #pragma unroll
  for (int i = 0; i < 8; i++) {
    int c = t + i*256;
    yr[c] = f2b(v[i]*scale*nw[c]);
  }
}

extern "C" void kernel_launch(void* const* d_in, const int* in_sizes, int n_in,
                              void* d_out, int out_size, void* d_ws, size_t ws_size,
                              hipStream_t stream)
{
  const float* x    = (const float*)d_in[0];
  const float* lnw  = (const float*)d_in[1];
  const float* lnb  = (const float*)d_in[2];
  const float* win  = (const float*)d_in[3];
  const float* cw   = (const float*)d_in[4];
  const float* cb   = (const float*)d_in[5];
  const float* dtb  = (const float*)d_in[6];
  const float* alog = (const float*)d_in[7];
  const float* dvec = (const float*)d_in[8];
  const float* nw   = (const float*)d_in[9];
  const float* wout = (const float*)d_in[10];
  float* out = (float*)d_out;
  char* ws = (char*)d_ws;
  (void)in_sizes; (void)n_in; (void)out_size;

  if (ws_size < B_END) return;  // workspace too small: fail cleanly, don't fault

  ushort* zb   = (ushort*)(ws + B_Z);
  ushort* xbcb = (ushort*)(ws + B_XBC);
  float*  dtr  = (float*) (ws + B_DT);
  ushort* xsb  = (ushort*)(ws + B_XS);
  ushort* bcb  = (ushort*)(ws + B_BC);
  ushort* yb   = (ushort*)(ws + B_Y);
  float*  asum = (float*) (ws + B_ASUM);
  ushort* Sb   = xbcb;                                        // aliases xbc (dead after conv)
  ushort* hb   = yb;                                          // aliases y[0 : 16.8MB]
  ushort* winB = (ushort*)(ws + B_Y + (size_t)ROWS*DMODEL*2); // aliases y[16.8MB : 26MB]
  ushort* woutB= (ushort*)(ws + B_XBC + (size_t)BATCH*NCHUNK*NHEADS*HEADDIM*DSTATE*2); // XBC tail (4.19MB)

  hipLaunchKernelGGL(convert_win_kernel, dim3((NPAD*DMODEL)/256), dim3(256), 0, stream, win, winB);
  hipLaunchKernelGGL(ln_kernel, dim3(ROWS), dim3(256), 0, stream, x, lnw, lnb, hb);
  hipLaunchKernelGGL(gemm_inproj_mfma, dim3(64, 35), dim3(256), 0, stream, hb, winB, zb, xbcb, dtr, dtb);
  hipLaunchKernelGGL(conv_tiled, dim3(9, ROWS/32), dim3(256), 0, stream, xbcb, cw, cb, xsb, bcb);
  hipLaunchKernelGGL(convert_wout_kernel, dim3((DMODEL*DINNER)/256), dim3(256), 0, stream, wout, woutB);
  hipLaunchKernelGGL(states_mfma, dim3(NHEADS, NCHUNK, BATCH), dim3(256), 0, stream,
                     xsb, bcb, dtr, alog, Sb, asum);
  hipLaunchKernelGGL(scan_kernel, dim3(NHEADS, 4, BATCH), dim3(256), 0, stream, Sb, asum);
  hipLaunchKernelGGL(yssd_mfma, dim3(NHEADS, NCHUNK, BATCH), dim3(256), 0, stream,
                     xsb, bcb, dtr, alog, dvec, Sb, yb);
  hipLaunchKernelGGL(rmsnorm_kernel, dim3(ROWS), dim3(256), 0, stream, yb, zb, nw);
  hipLaunchKernelGGL(gemm_outproj_mfma, dim3(64, 8), dim3(256), 0, stream, yb, woutB, x, out);
}